// Round 8
// baseline (272.644 us; speedup 1.0000x reference)
//
#include <hip/hip_runtime.h>

typedef unsigned short u16;
typedef unsigned char u8;
typedef unsigned long long u64;
typedef short s16x8 __attribute__((ext_vector_type(8)));
typedef float f32x4 __attribute__((ext_vector_type(4)));
typedef int i32x4 __attribute__((ext_vector_type(4)));
typedef int i32x8 __attribute__((ext_vector_type(8)));

#define NN 8192
#define DD 512
#define KCAT 576

__device__ __forceinline__ u16 f2bf(float f) {
  unsigned u = __float_as_uint(f);
  unsigned r = u + 0x7fffu + ((u >> 16) & 1u);
  return (u16)(r >> 16);
}
__device__ __forceinline__ float bf2f(u16 s) {
  return __uint_as_float(((unsigned)s) << 16);
}
__device__ __forceinline__ void gld16(const void* g, void* l) {
  __builtin_amdgcn_global_load_lds((const __attribute__((address_space(1))) void*)g,
                                   (__attribute__((address_space(3))) void*)l, 16, 0, 0);
}
__device__ __forceinline__ int pk8(float f0, float f1, float f2, float f3) {
  int p = __builtin_amdgcn_cvt_pk_fp8_f32(f0, f1, 0, 0);
  p = __builtin_amdgcn_cvt_pk_fp8_f32(f2, f3, p, 1);
  return p;
}

// ---------- merged prep: [0,5): matvecs; [5,293): WcT; [293,2597): X ----------
__global__ void k_prep(const float* __restrict__ Wk, const float* __restrict__ Wq,
                       const float* __restrict__ bk, const float* __restrict__ bq,
                       const float* __restrict__ a, const float* __restrict__ Wm,
                       const float* __restrict__ Wg, const float* __restrict__ h,
                       const float* __restrict__ z, float* __restrict__ wk_a,
                       float* __restrict__ wq_a, float* __restrict__ sc,
                       u16* __restrict__ WcT, u16* __restrict__ X) {
  const int b = blockIdx.x, t = threadIdx.x;
  if (b < 5) {
    if (b < 2) {
      int c = b * 256 + t;
      float s = 0.f;
      for (int d = 0; d < 512; d++) s += Wk[(size_t)c * 512 + d] * a[d];
      wk_a[c] = s;
    } else if (b < 4) {
      int c = (b - 2) * 256 + t;
      float s = 0.f;
      for (int d = 0; d < 512; d++) s += Wq[(size_t)c * 512 + d] * a[512 + d];
      wq_a[c] = s;
    } else {
      __shared__ float red[8];
      int lane = t & 63, w = t >> 6;
      float s1 = bk[t] * a[t] + bk[t + 256] * a[t + 256];
      float s2 = bq[t] * a[512 + t] + bq[t + 256] * a[768 + t];
      #pragma unroll
      for (int o = 32; o >= 1; o >>= 1) { s1 += __shfl_down(s1, o); s2 += __shfl_down(s2, o); }
      if (lane == 0) { red[w] = s1; red[4 + w] = s2; }
      __syncthreads();
      if (t == 0) {
        sc[0] = red[0] + red[1] + red[2] + red[3];
        sc[1] = red[4] + red[5] + red[6] + red[7];
      }
    }
  } else if (b < 293) {
    int tid = (b - 5) * 256 + t;
    int n = tid / 72, g = tid % 72;
    int lg = (g & ~7) | ((g & 7) ^ (n & 7));
    int k0 = lg * 8;
    s16x8 o;
    #pragma unroll
    for (int e = 0; e < 8; e++) {
      int k = k0 + e;
      float val;
      if (n < 512) val = (k < 512) ? Wm[(size_t)k * 512 + n] : 0.f;
      else         val = Wg[(size_t)k * 512 + (n - 512)];
      o[e] = (short)f2bf(val);
    }
    *(s16x8*)&WcT[(size_t)n * KCAT + g * 8] = o;
  } else {
    int tid = (b - 293) * 256 + t;
    int i = tid / 72, g = tid % 72;
    int lg = (g & ~7) | ((g & 7) ^ (i & 7));
    int k0 = lg * 8;
    s16x8 o;
    if (k0 < 512) {
      const f32x4* s = (const f32x4*)(h + (size_t)i * 512 + k0);
      f32x4 v0 = s[0], v1 = s[1];
      #pragma unroll
      for (int e = 0; e < 4; e++) { o[e] = (short)f2bf(v0[e]); o[e + 4] = (short)f2bf(v1[e]); }
    } else {
      const f32x4* s = (const f32x4*)(z + (size_t)i * 64 + (k0 - 512));
      f32x4 v0 = s[0], v1 = s[1];
      #pragma unroll
      for (int e = 0; e < 4; e++) { o[e] = (short)f2bf(v0[e]); o[e + 4] = (short)f2bf(v1[e]); }
    }
    *(s16x8*)&X[(size_t)i * KCAT + g * 8] = o;
  }
}

// ---------- GEMM1: [8192x576] @ [576x1024] -> rm (relu), gate (sigmoid), l1 partials ----
__global__ __launch_bounds__(256) void k_gemm1(const u16* __restrict__ X,
    const u16* __restrict__ W, const float* __restrict__ bm, const float* __restrict__ bg,
    u16* __restrict__ rm, u16* __restrict__ gate, float* __restrict__ l1part) {
  __shared__ __align__(16) u16 As[128 * 64];
  __shared__ __align__(16) u16 Bs[128 * 64];
  __shared__ float red[4];
  const int t = threadIdx.x, bid = blockIdx.x;
  const int i0 = (bid & 63) * 128, n0 = (bid >> 6) * 128;
  const int lane = t & 63, w = t >> 6;
  const int lr = lane & 15, lh = lane >> 4;
  const int wm = (w >> 1) * 64, wn = (w & 1) * 64;
  const f32x4 vz = {0.f, 0.f, 0.f, 0.f};
  f32x4 acc[4][4];
  #pragma unroll
  for (int a_ = 0; a_ < 4; a_++)
    #pragma unroll
    for (int b_ = 0; b_ < 4; b_++) acc[a_][b_] = vz;

  for (int step = 0; step < 9; step++) {
    const int kk = step * 64;
    __syncthreads();
    #pragma unroll
    for (int c = 0; c < 4; c++) {
      int L = c * 256 + t;
      int row = L >> 3, ch = L & 7;
      gld16(X + (size_t)(i0 + row) * KCAT + kk + ch * 8, &As[L * 8]);
      gld16(W + (size_t)(n0 + row) * KCAT + kk + ch * 8, &Bs[L * 8]);
    }
    asm volatile("s_waitcnt vmcnt(0)" ::: "memory");
    __syncthreads();
    #pragma unroll
    for (int ks = 0; ks < 2; ks++) {
      s16x8 af[4], bfv[4];
      #pragma unroll
      for (int mr = 0; mr < 4; mr++) {
        int row = wm + mr * 16 + lr;
        int ch = (ks * 4 + lh) ^ (row & 7);
        af[mr] = *(const s16x8*)&As[row * 64 + ch * 8];
      }
      #pragma unroll
      for (int nr = 0; nr < 4; nr++) {
        int nn = wn + nr * 16 + lr;
        int ch = (ks * 4 + lh) ^ (nn & 7);
        bfv[nr] = *(const s16x8*)&Bs[nn * 64 + ch * 8];
      }
      #pragma unroll
      for (int mr = 0; mr < 4; mr++)
        #pragma unroll
        for (int nr = 0; nr < 4; nr++)
          acc[mr][nr] = __builtin_amdgcn_mfma_f32_16x16x32_bf16(af[mr], bfv[nr], acc[mr][nr], 0, 0, 0);
    }
  }
  float lsum = 0.f;
  #pragma unroll
  for (int nr = 0; nr < 4; nr++) {
    int nn = n0 + wn + nr * 16 + lr;
    bool ismsg = nn < 512;
    float bias = ismsg ? bm[nn] : bg[nn - 512];
    #pragma unroll
    for (int mr = 0; mr < 4; mr++) {
      #pragma unroll
      for (int r = 0; r < 4; r++) {
        int row = i0 + wm + mr * 16 + lh * 4 + r;
        float v0 = acc[mr][nr][r] + bias;
        if (ismsg) {
          rm[(size_t)row * 512 + nn] = f2bf(fmaxf(v0, 0.f));
        } else {
          float g = 1.f / (1.f + __expf(-v0));
          gate[(size_t)row * 512 + (nn - 512)] = f2bf(g);
          lsum += g;
        }
      }
    }
  }
  #pragma unroll
  for (int o = 32; o >= 1; o >>= 1) lsum += __shfl_down(lsum, o);
  if (lane == 0) red[w] = lsum;
  __syncthreads();
  if (t == 0) l1part[bid] = red[0] + red[1] + red[2] + red[3];
}

// ---------- per-row: gm = gate*rm (bf16), sk, sq, u=e^sk, v=e^.01sk ----------
__global__ __launch_bounds__(256) void k_rowact(const u16* __restrict__ rm,
    const u16* __restrict__ gate, const float* __restrict__ h,
    const float* __restrict__ wk_a, const float* __restrict__ wq_a,
    const float* __restrict__ sc, u16* __restrict__ gm, float* __restrict__ skv,
    float* __restrict__ sqv, float* __restrict__ uu, float* __restrict__ vv) {
  __shared__ float red[8];
  const int i = blockIdx.x, t = threadIdx.x;
  const int lane = t & 63, w = t >> 6;
  float sqp = 0.f, skp = 0.f;
  #pragma unroll
  for (int rep = 0; rep < 2; rep++) {
    int d = rep * 256 + t;
    float g = bf2f(gate[(size_t)i * 512 + d]);
    float r = bf2f(rm[(size_t)i * 512 + d]);
    float p = g * r;
    gm[(size_t)i * 512 + d] = f2bf(p);
    sqp += p * wq_a[d];
    skp += h[(size_t)i * 512 + d] * wk_a[d];
  }
  #pragma unroll
  for (int o = 32; o >= 1; o >>= 1) { sqp += __shfl_down(sqp, o); skp += __shfl_down(skp, o); }
  if (lane == 0) { red[w] = skp; red[4 + w] = sqp; }
  __syncthreads();
  if (t == 0) {
    float skt = red[0] + red[1] + red[2] + red[3] + sc[0];
    float sqt = red[4] + red[5] + red[6] + red[7] + sc[1];
    skv[i] = skt; sqv[i] = sqt;
    uu[i] = __expf(skt); vv[i] = __expf(0.01f * skt);
  }
}

// ---------- fused: streaming bitpack of adj + per-row softmax stats -> bits, P, Q ----
__global__ __launch_bounds__(256) void k_packstats(const int* __restrict__ adj,
    const float* __restrict__ sk, const float* __restrict__ uu, const float* __restrict__ vv,
    const float* __restrict__ sq, u64* __restrict__ bits,
    float* __restrict__ P, float* __restrict__ Q) {
  __shared__ u16 nib[512];
  __shared__ float red[12];
  const int t = threadIdx.x, lane = t & 63, w = t >> 6;
  const size_t i = blockIdx.x;
  const float sqi = sq[i];
  const float nsq = -sqi;
  float zp = 0.f, zn = 0.f, mx = -3.0e38f;
  #pragma unroll
  for (int k = 0; k < 2; k++) {
    const int j16 = (t + 256 * k) * 16;
    const int4* src = (const int4*)(adj + i * NN + j16);
    unsigned m = 0;
    #pragma unroll
    for (int q = 0; q < 4; q++) {
      int4 v = src[q];
      const int jb = j16 + q * 4;
      f32x4 s4 = *(const f32x4*)(sk + jb);
      f32x4 u4 = *(const f32x4*)(uu + jb);
      f32x4 w4 = *(const f32x4*)(vv + jb);
      int av0 = v.x, av1 = v.y, av2 = v.z, av3 = v.w;
      bool b0 = av0 > 0, b1 = av1 > 0, b2 = av2 > 0, b3 = av3 > 0;
      m |= (b0 ? 1u : 0u) << (q * 4);
      m |= (b1 ? 2u : 0u) << (q * 4);
      m |= (b2 ? 4u : 0u) << (q * 4);
      m |= (b3 ? 8u : 0u) << (q * 4);
      mx = fmaxf(fmaxf(mx, fmaxf(s4[0], s4[1])), fmaxf(s4[2], s4[3]));
      bool p0 = s4[0] > nsq, p1 = s4[1] > nsq, p2 = s4[2] > nsq, p3 = s4[3] > nsq;
      zp += (b0 && p0) ? u4[0] : 0.f;  zn += (b0 && !p0) ? w4[0] : 0.f;
      zp += (b1 && p1) ? u4[1] : 0.f;  zn += (b1 && !p1) ? w4[1] : 0.f;
      zp += (b2 && p2) ? u4[2] : 0.f;  zn += (b2 && !p2) ? w4[2] : 0.f;
      zp += (b3 && p3) ? u4[3] : 0.f;  zn += (b3 && !p3) ? w4[3] : 0.f;
    }
    nib[k * 256 + t] = (u16)m;
  }
  #pragma unroll
  for (int o = 32; o >= 1; o >>= 1) {
    zp += __shfl_down(zp, o);
    zn += __shfl_down(zn, o);
    mx = fmaxf(mx, __shfl_down(mx, o));
  }
  if (lane == 0) { red[w] = zp; red[4 + w] = zn; red[8 + w] = mx; }
  __syncthreads();
  if (t == 0) {
    float ZP = red[0] + red[1] + red[2] + red[3];
    float ZN = red[4] + red[5] + red[6] + red[7];
    float MX = fmaxf(fmaxf(red[8], red[9]), fmaxf(red[10], red[11]));
    float xk = sqi + MX;
    float m_i = xk >= 0.f ? xk : 0.01f * xk;
    float ep = __expf(sqi - m_i), en = __expf(0.01f * sqi - m_i);
    float Z = ep * ZP + en * ZN;
    float inv = 1.0f / Z;
    P[i] = ep * inv;
    Q[i] = en * inv;
  }
  if (t < 128) bits[i * 128 + t] = *(const u64*)&nib[t * 4];
}

// ---------- 64x64 bit-transpose via ballot (standalone, used by fallback) ----------
__global__ void k_bitT(const u64* __restrict__ bits, u64* __restrict__ bitT) {
  int wid = blockIdx.x * 4 + (threadIdx.x >> 6);
  int ti = wid & 127, tj = wid >> 7;
  int lane = threadIdx.x & 63;
  u64 w = bits[(size_t)(ti * 64 + lane) * 128 + tj];
  u64 out = 0;
  #pragma unroll
  for (int jj = 0; jj < 64; jj++) {
    u64 b = __ballot((int)((w >> jj) & 1ULL));
    if (jj == lane) out = b;
  }
  bitT[(size_t)(tj * 64 + lane) * 128 + ti] = out;
}

// ---------- fused: [0,1024) tgm8 (gm bf16 -> gmT8 fp8 x16, chunk16 swz); [1024,5120) bitT ----
__global__ __launch_bounds__(256) void k_tb(const u16* __restrict__ gm, u8* __restrict__ gmT8,
                                            const u64* __restrict__ bits, u64* __restrict__ bitT) {
  const int bid = blockIdx.x, t = threadIdx.x;
  if (bid < 1024) {
    __shared__ __align__(16) u16 tile[64][72];
    const int ti = bid & 127, td = bid >> 7;
    #pragma unroll
    for (int rep = 0; rep < 2; rep++) {
      int L = rep * 256 + t;
      int row = L >> 3, ch = L & 7;
      s16x8 val = *(const s16x8*)(gm + (size_t)(ti * 64 + row) * 512 + td * 64 + ch * 8);
      *(s16x8*)&tile[row][ch * 8] = val;
    }
    __syncthreads();
    const int dl = t >> 2, lc = t & 3;
    const int d = td * 64 + dl;
    const int chg = ti * 4 + lc;
    i32x4 o;
    #pragma unroll
    for (int q = 0; q < 4; q++) {
      int ib = lc * 16 + q * 4;
      o[q] = pk8(bf2f(tile[ib][dl]) * 16.f, bf2f(tile[ib + 1][dl]) * 16.f,
                 bf2f(tile[ib + 2][dl]) * 16.f, bf2f(tile[ib + 3][dl]) * 16.f);
    }
    *(i32x4*)(gmT8 + (size_t)d * NN + (chg >> 3) * 128 + ((chg & 7) ^ (d & 7)) * 16) = o;
  } else {
    int wid = (bid - 1024) * 4 + (t >> 6);
    int ti = wid & 127, tj = wid >> 7;
    int lane = t & 63;
    u64 w = bits[(size_t)(ti * 64 + lane) * 128 + tj];
    u64 out = 0;
    #pragma unroll
    for (int jj = 0; jj < 64; jj++) {
      u64 b = __ballot((int)((w >> jj) & 1ULL));
      if (jj == lane) out = b;
    }
    bitT[(size_t)(tj * 64 + lane) * 128 + ti] = out;
  }
}

// ---------- bf16 transpose (fallback path) ----------
__global__ __launch_bounds__(256) void k_tgm(const u16* __restrict__ gm, u16* __restrict__ gmT) {
  __shared__ __align__(16) u16 tile[64][72];
  const int bid = blockIdx.x;
  const int ti = bid & 127, td = bid >> 7;
  const int t = threadIdx.x;
  #pragma unroll
  for (int rep = 0; rep < 2; rep++) {
    int L = rep * 256 + t;
    int row = L >> 3, ch = L & 7;
    s16x8 val = *(const s16x8*)(gm + (size_t)(ti * 64 + row) * 512 + td * 64 + ch * 8);
    *(s16x8*)&tile[row][ch * 8] = val;
  }
  __syncthreads();
  #pragma unroll
  for (int rep = 0; rep < 2; rep++) {
    int L = rep * 256 + t;
    int dr = L >> 3, ig = L & 7;
    int d = td * 64 + dr;
    s16x8 o;
    #pragma unroll
    for (int e = 0; e < 8; e++) o[e] = (short)tile[ig * 8 + e][dr];
    *(s16x8*)(gmT + (size_t)d * NN + ti * 64 + (ig ^ (d & 7)) * 8) = o;
  }
}

// ---------- OLD row stats (fallback path only) ----------
__global__ __launch_bounds__(256) void k_rowstats(const int* __restrict__ adj,
    const float* __restrict__ sk, const float* __restrict__ sq,
    u64* __restrict__ bits, float* __restrict__ P, float* __restrict__ Q) {
  __shared__ float sks[NN];
  __shared__ u64 bw[128];
  __shared__ float red[8];
  const int i = blockIdx.x, t = threadIdx.x;
  const int lane = t & 63, w = t >> 6;
  const int* arow = adj + (size_t)i * NN;
  float kmax = -3.0e38f;
  for (int c = 0; c < 32; c++) {
    int j = c * 256 + t;
    int av = arow[j];
    float skj = sk[j];
    sks[j] = skj;
    bool bit = av > 0;
    u64 m = __ballot(bit);
    if (lane == 0) bw[c * 4 + w] = m;
    if (bit) kmax = fmaxf(kmax, skj);
  }
  #pragma unroll
  for (int o = 32; o >= 1; o >>= 1) kmax = fmaxf(kmax, __shfl_down(kmax, o));
  if (lane == 0) red[w] = kmax;
  __syncthreads();
  float K = fmaxf(fmaxf(red[0], red[1]), fmaxf(red[2], red[3]));
  float sqi = sq[i];
  float xk = sqi + K;
  float m_i = xk >= 0.f ? xk : 0.01f * xk;
  float s = 0.f;
  for (int c = 0; c < 32; c++) {
    int j = c * 256 + t;
    u64 mw = bw[c * 4 + w];
    float xx = sqi + sks[j];
    float f = xx >= 0.f ? xx : 0.01f * xx;
    float e = __expf(f - m_i);
    if ((mw >> lane) & 1ULL) s += e;
  }
  #pragma unroll
  for (int o = 32; o >= 1; o >>= 1) s += __shfl_down(s, o);
  if (lane == 0) red[4 + w] = s;
  __syncthreads();
  if (t == 0) {
    float Z = red[4] + red[5] + red[6] + red[7];
    float inv = 1.0f / Z;
    P[i] = __expf(sqi - m_i) * inv;
    Q[i] = __expf(0.01f * sqi - m_i) * inv;
  }
  if (t < 128) bits[(size_t)i * 128 + t] = bw[t];
}

// ---------- attgen8: attT8[j][i] = fp8(att*256), chunk16 swizzle in 128-i windows ----
__global__ __launch_bounds__(256) void k_attgen8(const u64* __restrict__ bitT,
    const float* __restrict__ P, const float* __restrict__ Q, const float* __restrict__ sq,
    const float* __restrict__ u, const float* __restrict__ v, const float* __restrict__ sk,
    u8* __restrict__ attT8) {
  const int t = threadIdx.x, bid = blockIdx.x;
  const int jt = bid >> 1, ih = bid & 1;
  const int j0 = jt * 16;
  const int i0 = ih * 4096 + t * 16;
  f32x4 Pv[4], Qv[4], Sv[4];
  #pragma unroll
  for (int q = 0; q < 4; q++) {
    Pv[q] = *(const f32x4*)(P + i0 + q * 4);
    Qv[q] = *(const f32x4*)(Q + i0 + q * 4);
    Sv[q] = *(const f32x4*)(sq + i0 + q * 4);
  }
  const int widx = i0 >> 6;
  const int bsh = (t & 3) * 16;
  const int chg = i0 >> 4;
  const int wnd = chg >> 3, cs = chg & 7;
  #pragma unroll 2
  for (int r = 0; r < 16; r++) {
    const int j = j0 + r;
    const float uj = u[j] * 256.f, vj = v[j] * 256.f, nskj = -sk[j];
    const u64 w64 = bitT[(size_t)j * 128 + widx];
    const unsigned m16 = (unsigned)(w64 >> bsh) & 0xFFFFu;
    i32x4 o;
    #pragma unroll
    for (int q = 0; q < 4; q++) {
      float f[4];
      #pragma unroll
      for (int e = 0; e < 4; e++) {
        bool pos = Sv[q][e] > nskj;
        float val = pos ? Pv[q][e] * uj : Qv[q][e] * vj;
        f[e] = ((m16 >> (q * 4 + e)) & 1u) ? val : 0.f;
      }
      o[q] = pk8(f[0], f[1], f[2], f[3]);
    }
    *(i32x4*)(attT8 + (size_t)j * NN + wnd * 128 + ((cs ^ (j & 7)) * 16)) = o;
  }
}

// ---------- aggr8: MX-fp8 GEMM (K=128/step), pb[split][j][d] ----------
__device__ __forceinline__ i32x8 ld_frag8(const u8* base, int row, int lh) {
  const int c0 = ((2 * lh) ^ (row & 7)) * 16;
  const int c1 = ((2 * lh + 1) ^ (row & 7)) * 16;
  i32x4 lo = *(const i32x4*)(base + row * 128 + c0);
  i32x4 hi = *(const i32x4*)(base + row * 128 + c1);
  i32x8 r;
  r[0] = lo[0]; r[1] = lo[1]; r[2] = lo[2]; r[3] = lo[3];
  r[4] = hi[0]; r[5] = hi[1]; r[6] = hi[2]; r[7] = hi[3];
  return r;
}

__global__ __launch_bounds__(256) void k_aggr8(const u8* __restrict__ attT8,
    const u8* __restrict__ gmT8, u16* __restrict__ pb) {
  __shared__ __align__(16) u8 As[128 * 128];
  __shared__ __align__(16) u8 Bs[128 * 128];
  const int t = threadIdx.x, bid = blockIdx.x;
  const int lid = (bid & 7) * 128 + (bid >> 3);
  const int dt = lid & 3, jt = (lid >> 2) & 63, split = lid >> 8;
  const int j0 = jt * 128, d0 = dt * 128;
  const int lane = t & 63, w = t >> 6;
  const int lr = lane & 15, lh = lane >> 4;
  const int wm = (w >> 1) * 64, wn = (w & 1) * 64;
  const f32x4 vz = {0.f, 0.f, 0.f, 0.f};
  f32x4 acc[4][4];
  #pragma unroll
  for (int a_ = 0; a_ < 4; a_++)
    #pragma unroll
    for (int b_ = 0; b_ < 4; b_++) acc[a_][b_] = vz;

  for (int step = 0; step < 16; step++) {
    const int ss = split * 16 + step;
    __syncthreads();
    #pragma unroll
    for (int c = 0; c < 4; c++) {
      int idx = c * 256 + t;
      int row = idx >> 3, ch = idx & 7;
      gld16(attT8 + (size_t)(j0 + row) * NN + (size_t)ss * 128 + ch * 16, &As[idx * 16]);
      gld16(gmT8 + (size_t)(d0 + row) * NN + (size_t)ss * 128 + ch * 16, &Bs[idx * 16]);
    }
    asm volatile("s_waitcnt vmcnt(0)" ::: "memory");
    __syncthreads();
    i32x8 af[4], bfv[4];
    #pragma unroll
    for (int mr = 0; mr < 4; mr++) af[mr] = ld_frag8(As, wm + mr * 16 + lr, lh);
    #pragma unroll
    for (int nr = 0; nr < 4; nr++) bfv[nr] = ld_frag8(Bs, wn + nr * 16 + lr, lh);
    #pragma unroll
    for (int mr = 0; mr < 4; mr++)
      #pragma unroll
      for (int nr = 0; nr < 4; nr++)
        acc[mr][nr] = __builtin_amdgcn_mfma_scale_f32_16x16x128_f8f6f4(
            af[mr], bfv[nr], acc[mr][nr], 0, 0,
            0, 0x77777777,   // A scale: 2^-8 (att stored x256)
            0, 0x7B7B7B7B);  // B scale: 2^-4 (gm stored x16)
  }
  u16* pbs = pb + (size_t)split * NN * 512;
  #pragma unroll
  for (int mr = 0; mr < 4; mr++) {
    #pragma unroll
    for (int nr = 0; nr < 4; nr++) {
      int dn = d0 + wn + nr * 16 + lr;
      #pragma unroll
      for (int r = 0; r < 4; r++) {
        int jj = j0 + wm + mr * 16 + lh * 4 + r;
        pbs[(size_t)jj * 512 + dn] = f2bf(acc[mr][nr][r]);
      }
    }
  }
}

// ---------- OLD fused aggr (fallback when ws too small) ----------
__global__ __launch_bounds__(512) void k_aggr(const u16* __restrict__ gmT,
    const u64* __restrict__ bitT, const float* __restrict__ P, const float* __restrict__ Q,
    const float* __restrict__ sq, const float* __restrict__ u, const float* __restrict__ v,
    const float* __restrict__ sk, u16* __restrict__ pb) {
  __shared__ __align__(16) u16 Alds[128 * 64];
  __shared__ __align__(16) u16 Blds[128 * 64];
  const int t = threadIdx.x, bid = blockIdx.x;
  const int lid = (bid & 7) * 128 + (bid >> 3);
  const int j_t = lid & 63, rest = lid >> 6;
  const int split = rest & 3, d_t = rest >> 2;
  const int j0 = j_t * 128, d0 = d_t * 128;
  const int lane = t & 63, w = t >> 6;
  const int lr = lane & 15, lh = lane >> 4;
  const int wm = (w >> 1) * 32, wn = (w & 1) * 64;
  const int gj = t & 127, gq = t >> 7;
  const int jg = j0 + gj;
  const float uj = u[jg], vj = v[jg], nskj = -sk[jg];
  const u64* btrow = bitT + (size_t)jg * 128;
  const f32x4 vzero = {0.f, 0.f, 0.f, 0.f};
  f32x4 acc[2][4];
  #pragma unroll
  for (int a_ = 0; a_ < 2; a_++)
    #pragma unroll
    for (int b_ = 0; b_ < 4; b_++) acc[a_][b_] = vzero;

  for (int step = 0; step < 32; step++) {
    const int ss = split * 32 + step;
    __syncthreads();
    #pragma unroll
    for (int c = 0; c < 2; c++) {
      int L = c * 512 + t;
      int dd = L >> 3, ch = L & 7;
      gld16(gmT + (size_t)(d0 + dd) * NN + ss * 64 + ch * 8, &Blds[L * 8]);
    }
    u64 word = btrow[ss];
    #pragma unroll
    for (int cc = 0; cc < 2; cc++) {
      int ig = gq + cc * 4;
      int i8 = ss * 64 + ig * 8;
      const f32x4* P4 = (const f32x4*)(P + i8);
      const f32x4* Q4 = (const f32x4*)(Q + i8);
      const f32x4* S4 = (const f32x4*)(sq + i8);
      s16x8 rr;
      #pragma unroll
      for (int hf = 0; hf < 2; hf++) {
        f32x4 pv = P4[hf], qv = Q4[hf], sv = S4[hf];
        #pragma unroll
        for (int e = 0; e < 4; e++) {
          int ie = hf * 4 + e;
          float val = (sv[e] > nskj) ? pv[e] * uj : qv[e] * vj;
          bool bit = (word >> (ig * 8 + ie)) & 1ULL;
          rr[ie] = bit ? (short)f2bf(val) : (short)0;
        }
      }
      *(s16x8*)&Alds[gj * 64 + (ig ^ (gj & 7)) * 8] = rr;
    }
    asm volatile("s_waitcnt vmcnt(0)" ::: "memory");
    __syncthreads();
    #pragma unroll
    for (int ks = 0; ks < 2; ks++) {
      s16x8 af[2], bfv[4];
      #pragma unroll
      for (int mr = 0; mr < 2; mr++) {
        int row = wm + mr * 16 + lr;
        int ch = (ks * 4 + lh) ^ (row & 7);
        af[mr] = *(const s16x8*)&Alds[row * 64 + ch * 8];
      }
      #pragma unroll
      for (int nr = 0; nr < 4; nr++) {
        int dn = wn + nr * 16 + lr;
        int ch = (ks * 4 + lh) ^ (dn & 7);
        bfv[nr] = *(const s16x8*)&Blds[dn * 64 + ch * 8];
      }
      #pragma unroll
      for (int mr = 0; mr < 2; mr++)
        #pragma unroll
        for (int nr = 0; nr < 4; nr++)
          acc[mr][nr] = __builtin_amdgcn_mfma_f32_16x16x32_bf16(af[mr], bfv[nr], acc[mr][nr], 0, 0, 0);
    }
  }
  u16* pbs = pb + (size_t)split * NN * 512;
  #pragma unroll
  for (int mr = 0; mr < 2; mr++) {
    #pragma unroll
    for (int nr = 0; nr < 4; nr++) {
      int dn = d0 + wn + nr * 16 + lr;
      #pragma unroll
      for (int r = 0; r < 4; r++) {
        int jj = j0 + wm + mr * 16 + lh * 4 + r;
        pbs[(size_t)jj * 512 + dn] = f2bf(acc[mr][nr][r]);
      }
    }
  }
}

// ---------- reduce splits + (agg+h)/2; block 2048 finalizes the loss ----------
__global__ __launch_bounds__(256) void k_reduce(const u16* __restrict__ pb,
    const float* __restrict__ h, const float* __restrict__ part, float* __restrict__ out) {
  if (blockIdx.x == 2048) {
    __shared__ float red[4];
    int t = threadIdx.x, lane = t & 63, w = t >> 6;
    float s = part[t] + part[t + 256];
    #pragma unroll
    for (int o = 32; o >= 1; o >>= 1) s += __shfl_down(s, o);
    if (lane == 0) red[w] = s;
    __syncthreads();
    if (t == 0) out[(size_t)NN * 512] = (red[0] + red[1] + red[2] + red[3]) * (1.0f / 4194304.0f);
    return;
  }
  size_t base = ((size_t)blockIdx.x * 256 + threadIdx.x) * 8;
  s16x8 p0 = *(const s16x8*)(pb + base);
  s16x8 p1 = *(const s16x8*)(pb + (size_t)NN * 512 + base);
  s16x8 p2 = *(const s16x8*)(pb + (size_t)2 * NN * 512 + base);
  s16x8 p3 = *(const s16x8*)(pb + (size_t)3 * NN * 512 + base);
  f32x4 h0 = *(const f32x4*)(h + base);
  f32x4 h1 = *(const f32x4*)(h + base + 4);
  f32x4 o0, o1;
  #pragma unroll
  for (int e = 0; e < 4; e++) {
    o0[e] = (bf2f((u16)p0[e]) + bf2f((u16)p1[e]) + bf2f((u16)p2[e]) + bf2f((u16)p3[e]) + h0[e]) * 0.5f;
    o1[e] = (bf2f((u16)p0[e + 4]) + bf2f((u16)p1[e + 4]) + bf2f((u16)p2[e + 4]) + bf2f((u16)p3[e + 4]) + h1[e]) * 0.5f;
  }
  *(f32x4*)(out + base) = o0;
  *(f32x4*)(out + base + 4) = o1;
}

extern "C" void kernel_launch(void* const* d_in, const int* in_sizes, int n_in,
                              void* d_out, int out_size, void* d_ws, size_t ws_size,
                              hipStream_t stream) {
  const float* h  = (const float*)d_in[0];
  const int*   adj= (const int*)d_in[1];
  const float* z  = (const float*)d_in[2];
  const float* Wm = (const float*)d_in[3];
  const float* bm = (const float*)d_in[4];
  const float* Wg = (const float*)d_in[5];
  const float* bg = (const float*)d_in[6];
  const float* Wk = (const float*)d_in[7];
  const float* bk = (const float*)d_in[8];
  const float* Wq = (const float*)d_in[9];
  const float* bq = (const float*)d_in[10];
  const float* a  = (const float*)d_in[11];
  float* out = (float*)d_out;
  char* ws = (char*)d_ws;

  size_t off = 0;
  auto alloc = [&](size_t b) { size_t o = off; off += (b + 255) & ~(size_t)255; return o; };
  float* wk_a = (float*)(ws + alloc(512 * 4));
  float* wq_a = (float*)(ws + alloc(512 * 4));
  float* sc   = (float*)(ws + alloc(256));
  float* skv  = (float*)(ws + alloc(NN * 4));
  float* sqv  = (float*)(ws + alloc(NN * 4));
  float* uu   = (float*)(ws + alloc(NN * 4));
  float* vv   = (float*)(ws + alloc(NN * 4));
  float* Pp   = (float*)(ws + alloc(NN * 4));
  float* Qp   = (float*)(ws + alloc(NN * 4));
  float* l1p  = (float*)(ws + alloc(512 * 4));
  u16*   WcT  = (u16*)(ws + alloc((size_t)1024 * KCAT * 2));
  u16*   gmTb = (u16*)(ws + alloc((size_t)DD * NN * 2));      // bf16 gmT (fallback) / fp8 gmT8 (big)
  u64*   bitTb= (u64*)(ws + alloc((size_t)NN * 128 * 8));
  u16*   pb   = (u16*)(ws + alloc((size_t)4 * NN * 512 * 2));

  const size_t bigNeed = (size_t)NN * NN * 2;
  bool bigPath = (ws_size >= off + bigNeed);

  if (bigPath) {
    char* big = ws + alloc(bigNeed);
    u16* Xbf  = (u16*)big;                                    // prep -> gemm1
    u16* rm   = (u16*)(big + ((size_t)10 << 20));             // gemm1 -> rowact
    u16* gate = (u16*)(big + ((size_t)19 << 20));             // gemm1 -> rowact
    u16* gm   = (u16*)(big + ((size_t)28 << 20));             // rowact -> tb(tgm8)
    u64* bits = (u64*)big;                                    // packstats -> tb(bitT)
    u8*  attT8= (u8*)big;                                     // attgen8 -> aggr8 (64MB)
    u8*  gmT8 = (u8*)gmTb;                                    // fp8 gmT (4MB of slot)

    k_prep<<<2597, 256, 0, stream>>>(Wk, Wq, bk, bq, a, Wm, Wg, h, z,
                                     wk_a, wq_a, sc, WcT, Xbf);
    k_gemm1<<<512, 256, 0, stream>>>(Xbf, WcT, bm, bg, rm, gate, l1p);
    k_rowact<<<8192, 256, 0, stream>>>(rm, gate, h, wk_a, wq_a, sc, gm, skv, sqv, uu, vv);
    k_packstats<<<8192, 256, 0, stream>>>(adj, skv, uu, vv, sqv, bits, Pp, Qp);
    k_tb<<<5120, 256, 0, stream>>>(gm, gmT8, bits, bitTb);
    k_attgen8<<<1024, 256, 0, stream>>>(bitTb, Pp, Qp, sqv, uu, vv, skv, attT8);
    k_aggr8<<<1024, 256, 0, stream>>>(attT8, gmT8, pb);
    k_reduce<<<2049, 256, 0, stream>>>(pb, h, l1p, out);
  } else {
    char* regA = ws + alloc((size_t)NN * KCAT * 2);
    char* regB = ws + alloc((size_t)NN * 512 * 2);
    char* regC = ws + alloc((size_t)NN * 512 * 2);
    u16* Xbf = (u16*)regA;  u64* bits = (u64*)regA;
    u16* rm  = (u16*)regB;
    u16* gate= (u16*)regC;
    u16* gmv = (u16*)(ws + alloc((size_t)NN * 512 * 2));
    k_prep<<<2597, 256, 0, stream>>>(Wk, Wq, bk, bq, a, Wm, Wg, h, z,
                                     wk_a, wq_a, sc, WcT, Xbf);
    k_gemm1<<<512, 256, 0, stream>>>(Xbf, WcT, bm, bg, rm, gate, l1p);
    k_rowact<<<8192, 256, 0, stream>>>(rm, gate, h, wk_a, wq_a, sc, gmv, skv, sqv, uu, vv);
    k_tgm<<<1024, 256, 0, stream>>>(gmv, gmTb);
    k_rowstats<<<8192, 256, 0, stream>>>(adj, skv, sqv, bits, Pp, Qp);
    k_bitT<<<4096, 256, 0, stream>>>(bits, bitTb);
    k_aggr<<<1024, 512, 0, stream>>>(gmTb, bitTb, Pp, Qp, sqv, uu, vv, skv, pb);
    k_reduce<<<2049, 256, 0, stream>>>(pb, h, l1p, out);
  }
}

// Round 9
// 241.718 us; speedup vs baseline: 1.1279x; 1.1279x over previous
//
#include <hip/hip_runtime.h>

typedef unsigned short u16;
typedef unsigned char u8;
typedef unsigned long long u64;
typedef short s16x8 __attribute__((ext_vector_type(8)));
typedef float f32x4 __attribute__((ext_vector_type(4)));
typedef int i32x4 __attribute__((ext_vector_type(4)));
typedef int i32x8 __attribute__((ext_vector_type(8)));

#define NN 8192
#define DD 512
#define KCAT 576

__device__ __forceinline__ u16 f2bf(float f) {
  unsigned u = __float_as_uint(f);
  unsigned r = u + 0x7fffu + ((u >> 16) & 1u);
  return (u16)(r >> 16);
}
__device__ __forceinline__ float bf2f(u16 s) {
  return __uint_as_float(((unsigned)s) << 16);
}
__device__ __forceinline__ void gld16(const void* g, void* l) {
  __builtin_amdgcn_global_load_lds((const __attribute__((address_space(1))) void*)g,
                                   (__attribute__((address_space(3))) void*)l, 16, 0, 0);
}
__device__ __forceinline__ int pk8(float f0, float f1, float f2, float f3) {
  int p = __builtin_amdgcn_cvt_pk_fp8_f32(f0, f1, 0, 0);
  p = __builtin_amdgcn_cvt_pk_fp8_f32(f2, f3, p, 1);
  return p;
}

// ---------- merged prep: [0,5): matvecs; [5,293): WcT; [293,2597): X ----------
__global__ void k_prep(const float* __restrict__ Wk, const float* __restrict__ Wq,
                       const float* __restrict__ bk, const float* __restrict__ bq,
                       const float* __restrict__ a, const float* __restrict__ Wm,
                       const float* __restrict__ Wg, const float* __restrict__ h,
                       const float* __restrict__ z, float* __restrict__ wk_a,
                       float* __restrict__ wq_a, float* __restrict__ sc,
                       u16* __restrict__ WcT, u16* __restrict__ X) {
  const int b = blockIdx.x, t = threadIdx.x;
  if (b < 5) {
    if (b < 2) {
      int c = b * 256 + t;
      float s = 0.f;
      for (int d = 0; d < 512; d++) s += Wk[(size_t)c * 512 + d] * a[d];
      wk_a[c] = s;
    } else if (b < 4) {
      int c = (b - 2) * 256 + t;
      float s = 0.f;
      for (int d = 0; d < 512; d++) s += Wq[(size_t)c * 512 + d] * a[512 + d];
      wq_a[c] = s;
    } else {
      __shared__ float red[8];
      int lane = t & 63, w = t >> 6;
      float s1 = bk[t] * a[t] + bk[t + 256] * a[t + 256];
      float s2 = bq[t] * a[512 + t] + bq[t + 256] * a[768 + t];
      #pragma unroll
      for (int o = 32; o >= 1; o >>= 1) { s1 += __shfl_down(s1, o); s2 += __shfl_down(s2, o); }
      if (lane == 0) { red[w] = s1; red[4 + w] = s2; }
      __syncthreads();
      if (t == 0) {
        sc[0] = red[0] + red[1] + red[2] + red[3];
        sc[1] = red[4] + red[5] + red[6] + red[7];
      }
    }
  } else if (b < 293) {
    int tid = (b - 5) * 256 + t;
    int n = tid / 72, g = tid % 72;
    int lg = (g & ~7) | ((g & 7) ^ (n & 7));
    int k0 = lg * 8;
    s16x8 o;
    #pragma unroll
    for (int e = 0; e < 8; e++) {
      int k = k0 + e;
      float val;
      if (n < 512) val = (k < 512) ? Wm[(size_t)k * 512 + n] : 0.f;
      else         val = Wg[(size_t)k * 512 + (n - 512)];
      o[e] = (short)f2bf(val);
    }
    *(s16x8*)&WcT[(size_t)n * KCAT + g * 8] = o;
  } else {
    int tid = (b - 293) * 256 + t;
    int i = tid / 72, g = tid % 72;
    int lg = (g & ~7) | ((g & 7) ^ (i & 7));
    int k0 = lg * 8;
    s16x8 o;
    if (k0 < 512) {
      const f32x4* s = (const f32x4*)(h + (size_t)i * 512 + k0);
      f32x4 v0 = s[0], v1 = s[1];
      #pragma unroll
      for (int e = 0; e < 4; e++) { o[e] = (short)f2bf(v0[e]); o[e + 4] = (short)f2bf(v1[e]); }
    } else {
      const f32x4* s = (const f32x4*)(z + (size_t)i * 64 + (k0 - 512));
      f32x4 v0 = s[0], v1 = s[1];
      #pragma unroll
      for (int e = 0; e < 4; e++) { o[e] = (short)f2bf(v0[e]); o[e + 4] = (short)f2bf(v1[e]); }
    }
    *(s16x8*)&X[(size_t)i * KCAT + g * 8] = o;
  }
}

// ---------- GEMM1: [8192x576] @ [576x1024] -> rm (relu), gate (sigmoid), l1 partials ----
__global__ __launch_bounds__(256) void k_gemm1(const u16* __restrict__ X,
    const u16* __restrict__ W, const float* __restrict__ bm, const float* __restrict__ bg,
    u16* __restrict__ rm, u16* __restrict__ gate, float* __restrict__ l1part) {
  __shared__ __align__(16) u16 As[128 * 64];
  __shared__ __align__(16) u16 Bs[128 * 64];
  __shared__ float red[4];
  const int t = threadIdx.x, bid = blockIdx.x;
  const int i0 = (bid & 63) * 128, n0 = (bid >> 6) * 128;
  const int lane = t & 63, w = t >> 6;
  const int lr = lane & 15, lh = lane >> 4;
  const int wm = (w >> 1) * 64, wn = (w & 1) * 64;
  const f32x4 vz = {0.f, 0.f, 0.f, 0.f};
  f32x4 acc[4][4];
  #pragma unroll
  for (int a_ = 0; a_ < 4; a_++)
    #pragma unroll
    for (int b_ = 0; b_ < 4; b_++) acc[a_][b_] = vz;

  for (int step = 0; step < 9; step++) {
    const int kk = step * 64;
    __syncthreads();
    #pragma unroll
    for (int c = 0; c < 4; c++) {
      int L = c * 256 + t;
      int row = L >> 3, ch = L & 7;
      gld16(X + (size_t)(i0 + row) * KCAT + kk + ch * 8, &As[L * 8]);
      gld16(W + (size_t)(n0 + row) * KCAT + kk + ch * 8, &Bs[L * 8]);
    }
    asm volatile("s_waitcnt vmcnt(0)" ::: "memory");
    __syncthreads();
    #pragma unroll
    for (int ks = 0; ks < 2; ks++) {
      s16x8 af[4], bfv[4];
      #pragma unroll
      for (int mr = 0; mr < 4; mr++) {
        int row = wm + mr * 16 + lr;
        int ch = (ks * 4 + lh) ^ (row & 7);
        af[mr] = *(const s16x8*)&As[row * 64 + ch * 8];
      }
      #pragma unroll
      for (int nr = 0; nr < 4; nr++) {
        int nn = wn + nr * 16 + lr;
        int ch = (ks * 4 + lh) ^ (nn & 7);
        bfv[nr] = *(const s16x8*)&Bs[nn * 64 + ch * 8];
      }
      #pragma unroll
      for (int mr = 0; mr < 4; mr++)
        #pragma unroll
        for (int nr = 0; nr < 4; nr++)
          acc[mr][nr] = __builtin_amdgcn_mfma_f32_16x16x32_bf16(af[mr], bfv[nr], acc[mr][nr], 0, 0, 0);
    }
  }
  float lsum = 0.f;
  #pragma unroll
  for (int nr = 0; nr < 4; nr++) {
    int nn = n0 + wn + nr * 16 + lr;
    bool ismsg = nn < 512;
    float bias = ismsg ? bm[nn] : bg[nn - 512];
    #pragma unroll
    for (int mr = 0; mr < 4; mr++) {
      #pragma unroll
      for (int r = 0; r < 4; r++) {
        int row = i0 + wm + mr * 16 + lh * 4 + r;
        float v0 = acc[mr][nr][r] + bias;
        if (ismsg) {
          rm[(size_t)row * 512 + nn] = f2bf(fmaxf(v0, 0.f));
        } else {
          float g = 1.f / (1.f + __expf(-v0));
          gate[(size_t)row * 512 + (nn - 512)] = f2bf(g);
          lsum += g;
        }
      }
    }
  }
  #pragma unroll
  for (int o = 32; o >= 1; o >>= 1) lsum += __shfl_down(lsum, o);
  if (lane == 0) red[w] = lsum;
  __syncthreads();
  if (t == 0) l1part[bid] = red[0] + red[1] + red[2] + red[3];
}

// ---------- per-row: gm = gate*rm (bf16), sk, sq, u=e^sk, v=e^.01sk ----------
__global__ __launch_bounds__(256) void k_rowact(const u16* __restrict__ rm,
    const u16* __restrict__ gate, const float* __restrict__ h,
    const float* __restrict__ wk_a, const float* __restrict__ wq_a,
    const float* __restrict__ sc, u16* __restrict__ gm, float* __restrict__ skv,
    float* __restrict__ sqv, float* __restrict__ uu, float* __restrict__ vv) {
  __shared__ float red[8];
  const int i = blockIdx.x, t = threadIdx.x;
  const int lane = t & 63, w = t >> 6;
  float sqp = 0.f, skp = 0.f;
  #pragma unroll
  for (int rep = 0; rep < 2; rep++) {
    int d = rep * 256 + t;
    float g = bf2f(gate[(size_t)i * 512 + d]);
    float r = bf2f(rm[(size_t)i * 512 + d]);
    float p = g * r;
    gm[(size_t)i * 512 + d] = f2bf(p);
    sqp += p * wq_a[d];
    skp += h[(size_t)i * 512 + d] * wk_a[d];
  }
  #pragma unroll
  for (int o = 32; o >= 1; o >>= 1) { sqp += __shfl_down(sqp, o); skp += __shfl_down(skp, o); }
  if (lane == 0) { red[w] = skp; red[4 + w] = sqp; }
  __syncthreads();
  if (t == 0) {
    float skt = red[0] + red[1] + red[2] + red[3] + sc[0];
    float sqt = red[4] + red[5] + red[6] + red[7] + sc[1];
    skv[i] = skt; sqv[i] = sqt;
    uu[i] = __expf(skt); vv[i] = __expf(0.01f * skt);
  }
}

// ---------- streaming bitpack of adj (pure HBM streamer — keep lean) ----------
__global__ __launch_bounds__(256) void k_pack(const int* __restrict__ adj, u64* __restrict__ bits) {
  __shared__ u16 nib[512];
  const int t = threadIdx.x;
  const size_t i = blockIdx.x;
  #pragma unroll
  for (int k = 0; k < 2; k++) {
    const int4* src = (const int4*)(adj + i * NN + (size_t)(t + 256 * k) * 16);
    unsigned m = 0;
    #pragma unroll
    for (int q = 0; q < 4; q++) {
      int4 v = src[q];
      m |= (v.x > 0 ? 1u : 0u) << (4 * q);
      m |= (v.y > 0 ? 2u : 0u) << (4 * q);
      m |= (v.z > 0 ? 4u : 0u) << (4 * q);
      m |= (v.w > 0 ? 8u : 0u) << (4 * q);
    }
    nib[k * 256 + t] = (u16)m;
  }
  __syncthreads();
  if (t < 128) bits[i * 128 + t] = *(const u64*)&nib[t * 4];
}

// ---------- per-row softmax stats from bits (global-max stabilizer, in-loop) ----------
__global__ __launch_bounds__(256) void k_stats(const u64* __restrict__ bits,
    const float* __restrict__ sk, const float* __restrict__ uu, const float* __restrict__ vv,
    const float* __restrict__ sq, float* __restrict__ P, float* __restrict__ Q) {
  const int t = threadIdx.x, lane = t & 63, wv = t >> 6;
  const int i = blockIdx.x * 4 + wv;
  const float sqi = sq[i];
  const float nsq = -sqi;
  const u64* brow = bits + (size_t)i * 128;
  float zp = 0.f, zn = 0.f, m_loc = -3.0e38f;
  for (int k = 0; k < 128; k++) {
    u64 word = brow[k];
    float skj = sk[k * 64 + lane];
    float uj = uu[k * 64 + lane];
    float vj = vv[k * 64 + lane];
    m_loc = fmaxf(m_loc, skj);
    bool msk = (word >> lane) & 1ULL;
    bool pos = skj > nsq;
    zp += (msk && pos) ? uj : 0.f;
    zn += (msk && !pos) ? vj : 0.f;
  }
  #pragma unroll
  for (int o = 32; o >= 1; o >>= 1) {
    zp += __shfl_down(zp, o);
    zn += __shfl_down(zn, o);
    m_loc = fmaxf(m_loc, __shfl_down(m_loc, o));
  }
  if (lane == 0) {
    float xk = sqi + m_loc;
    float m_i = xk >= 0.f ? xk : 0.01f * xk;
    float ep = __expf(sqi - m_i), en = __expf(0.01f * sqi - m_i);
    float Z = ep * zp + en * zn;
    float inv = 1.0f / Z;
    P[i] = ep * inv;
    Q[i] = en * inv;
  }
}

// ---------- 64x64 bit-transpose via ballot (standalone, used by fallback) ----------
__global__ void k_bitT(const u64* __restrict__ bits, u64* __restrict__ bitT) {
  int wid = blockIdx.x * 4 + (threadIdx.x >> 6);
  int ti = wid & 127, tj = wid >> 7;
  int lane = threadIdx.x & 63;
  u64 w = bits[(size_t)(ti * 64 + lane) * 128 + tj];
  u64 out = 0;
  #pragma unroll
  for (int jj = 0; jj < 64; jj++) {
    u64 b = __ballot((int)((w >> jj) & 1ULL));
    if (jj == lane) out = b;
  }
  bitT[(size_t)(tj * 64 + lane) * 128 + ti] = out;
}

// ---------- fused: [0,1024) tgm8 (gm bf16 -> gmT8 fp8 x16, chunk16 swz); [1024,5120) bitT ----
__global__ __launch_bounds__(256) void k_tb(const u16* __restrict__ gm, u8* __restrict__ gmT8,
                                            const u64* __restrict__ bits, u64* __restrict__ bitT) {
  const int bid = blockIdx.x, t = threadIdx.x;
  if (bid < 1024) {
    __shared__ __align__(16) u16 tile[64][72];
    const int ti = bid & 127, td = bid >> 7;
    #pragma unroll
    for (int rep = 0; rep < 2; rep++) {
      int L = rep * 256 + t;
      int row = L >> 3, ch = L & 7;
      s16x8 val = *(const s16x8*)(gm + (size_t)(ti * 64 + row) * 512 + td * 64 + ch * 8);
      *(s16x8*)&tile[row][ch * 8] = val;
    }
    __syncthreads();
    const int dl = t >> 2, lc = t & 3;
    const int d = td * 64 + dl;
    const int chg = ti * 4 + lc;
    i32x4 o;
    #pragma unroll
    for (int q = 0; q < 4; q++) {
      int ib = lc * 16 + q * 4;
      o[q] = pk8(bf2f(tile[ib][dl]) * 16.f, bf2f(tile[ib + 1][dl]) * 16.f,
                 bf2f(tile[ib + 2][dl]) * 16.f, bf2f(tile[ib + 3][dl]) * 16.f);
    }
    *(i32x4*)(gmT8 + (size_t)d * NN + (chg >> 3) * 128 + ((chg & 7) ^ (d & 7)) * 16) = o;
  } else {
    int wid = (bid - 1024) * 4 + (t >> 6);
    int ti = wid & 127, tj = wid >> 7;
    int lane = t & 63;
    u64 w = bits[(size_t)(ti * 64 + lane) * 128 + tj];
    u64 out = 0;
    #pragma unroll
    for (int jj = 0; jj < 64; jj++) {
      u64 b = __ballot((int)((w >> jj) & 1ULL));
      if (jj == lane) out = b;
    }
    bitT[(size_t)(tj * 64 + lane) * 128 + ti] = out;
  }
}

// ---------- bf16 transpose (fallback path) ----------
__global__ __launch_bounds__(256) void k_tgm(const u16* __restrict__ gm, u16* __restrict__ gmT) {
  __shared__ __align__(16) u16 tile[64][72];
  const int bid = blockIdx.x;
  const int ti = bid & 127, td = bid >> 7;
  const int t = threadIdx.x;
  #pragma unroll
  for (int rep = 0; rep < 2; rep++) {
    int L = rep * 256 + t;
    int row = L >> 3, ch = L & 7;
    s16x8 val = *(const s16x8*)(gm + (size_t)(ti * 64 + row) * 512 + td * 64 + ch * 8);
    *(s16x8*)&tile[row][ch * 8] = val;
  }
  __syncthreads();
  #pragma unroll
  for (int rep = 0; rep < 2; rep++) {
    int L = rep * 256 + t;
    int dr = L >> 3, ig = L & 7;
    int d = td * 64 + dr;
    s16x8 o;
    #pragma unroll
    for (int e = 0; e < 8; e++) o[e] = (short)tile[ig * 8 + e][dr];
    *(s16x8*)(gmT + (size_t)d * NN + ti * 64 + (ig ^ (d & 7)) * 8) = o;
  }
}

// ---------- OLD row stats (fallback path only) ----------
__global__ __launch_bounds__(256) void k_rowstats(const int* __restrict__ adj,
    const float* __restrict__ sk, const float* __restrict__ sq,
    u64* __restrict__ bits, float* __restrict__ P, float* __restrict__ Q) {
  __shared__ float sks[NN];
  __shared__ u64 bw[128];
  __shared__ float red[8];
  const int i = blockIdx.x, t = threadIdx.x;
  const int lane = t & 63, w = t >> 6;
  const int* arow = adj + (size_t)i * NN;
  float kmax = -3.0e38f;
  for (int c = 0; c < 32; c++) {
    int j = c * 256 + t;
    int av = arow[j];
    float skj = sk[j];
    sks[j] = skj;
    bool bit = av > 0;
    u64 m = __ballot(bit);
    if (lane == 0) bw[c * 4 + w] = m;
    if (bit) kmax = fmaxf(kmax, skj);
  }
  #pragma unroll
  for (int o = 32; o >= 1; o >>= 1) kmax = fmaxf(kmax, __shfl_down(kmax, o));
  if (lane == 0) red[w] = kmax;
  __syncthreads();
  float K = fmaxf(fmaxf(red[0], red[1]), fmaxf(red[2], red[3]));
  float sqi = sq[i];
  float xk = sqi + K;
  float m_i = xk >= 0.f ? xk : 0.01f * xk;
  float s = 0.f;
  for (int c = 0; c < 32; c++) {
    int j = c * 256 + t;
    u64 mw = bw[c * 4 + w];
    float xx = sqi + sks[j];
    float f = xx >= 0.f ? xx : 0.01f * xx;
    float e = __expf(f - m_i);
    if ((mw >> lane) & 1ULL) s += e;
  }
  #pragma unroll
  for (int o = 32; o >= 1; o >>= 1) s += __shfl_down(s, o);
  if (lane == 0) red[4 + w] = s;
  __syncthreads();
  if (t == 0) {
    float Z = red[4] + red[5] + red[6] + red[7];
    float inv = 1.0f / Z;
    P[i] = __expf(sqi - m_i) * inv;
    Q[i] = __expf(0.01f * sqi - m_i) * inv;
  }
  if (t < 128) bits[(size_t)i * 128 + t] = bw[t];
}

// ---------- attgen8: attT8[j][i] = fp8(att*256), chunk16 swizzle in 128-i windows ----
__global__ __launch_bounds__(256) void k_attgen8(const u64* __restrict__ bitT,
    const float* __restrict__ P, const float* __restrict__ Q, const float* __restrict__ sq,
    const float* __restrict__ u, const float* __restrict__ v, const float* __restrict__ sk,
    u8* __restrict__ attT8) {
  const int t = threadIdx.x, bid = blockIdx.x;
  const int jt = bid >> 1, ih = bid & 1;
  const int j0 = jt * 16;
  const int i0 = ih * 4096 + t * 16;
  f32x4 Pv[4], Qv[4], Sv[4];
  #pragma unroll
  for (int q = 0; q < 4; q++) {
    Pv[q] = *(const f32x4*)(P + i0 + q * 4);
    Qv[q] = *(const f32x4*)(Q + i0 + q * 4);
    Sv[q] = *(const f32x4*)(sq + i0 + q * 4);
  }
  const int widx = i0 >> 6;
  const int bsh = (t & 3) * 16;
  const int chg = i0 >> 4;
  const int wnd = chg >> 3, cs = chg & 7;
  #pragma unroll 2
  for (int r = 0; r < 16; r++) {
    const int j = j0 + r;
    const float uj = u[j] * 256.f, vj = v[j] * 256.f, nskj = -sk[j];
    const u64 w64 = bitT[(size_t)j * 128 + widx];
    const unsigned m16 = (unsigned)(w64 >> bsh) & 0xFFFFu;
    i32x4 o;
    #pragma unroll
    for (int q = 0; q < 4; q++) {
      float f[4];
      #pragma unroll
      for (int e = 0; e < 4; e++) {
        bool pos = Sv[q][e] > nskj;
        float val = pos ? Pv[q][e] * uj : Qv[q][e] * vj;
        f[e] = ((m16 >> (q * 4 + e)) & 1u) ? val : 0.f;
      }
      o[q] = pk8(f[0], f[1], f[2], f[3]);
    }
    *(i32x4*)(attT8 + (size_t)j * NN + wnd * 128 + ((cs ^ (j & 7)) * 16)) = o;
  }
}

// ---------- aggr8: MX-fp8 GEMM (K=128/step), pb[split][j][d] ----------
__device__ __forceinline__ i32x8 ld_frag8(const u8* base, int row, int lh) {
  const int c0 = ((2 * lh) ^ (row & 7)) * 16;
  const int c1 = ((2 * lh + 1) ^ (row & 7)) * 16;
  i32x4 lo = *(const i32x4*)(base + row * 128 + c0);
  i32x4 hi = *(const i32x4*)(base + row * 128 + c1);
  i32x8 r;
  r[0] = lo[0]; r[1] = lo[1]; r[2] = lo[2]; r[3] = lo[3];
  r[4] = hi[0]; r[5] = hi[1]; r[6] = hi[2]; r[7] = hi[3];
  return r;
}

__global__ __launch_bounds__(256) void k_aggr8(const u8* __restrict__ attT8,
    const u8* __restrict__ gmT8, u16* __restrict__ pb) {
  __shared__ __align__(16) u8 As[128 * 128];
  __shared__ __align__(16) u8 Bs[128 * 128];
  const int t = threadIdx.x, bid = blockIdx.x;
  const int lid = (bid & 7) * 128 + (bid >> 3);
  const int dt = lid & 3, jt = (lid >> 2) & 63, split = lid >> 8;
  const int j0 = jt * 128, d0 = dt * 128;
  const int lane = t & 63, w = t >> 6;
  const int lr = lane & 15, lh = lane >> 4;
  const int wm = (w >> 1) * 64, wn = (w & 1) * 64;
  const f32x4 vz = {0.f, 0.f, 0.f, 0.f};
  f32x4 acc[4][4];
  #pragma unroll
  for (int a_ = 0; a_ < 4; a_++)
    #pragma unroll
    for (int b_ = 0; b_ < 4; b_++) acc[a_][b_] = vz;

  for (int step = 0; step < 16; step++) {
    const int ss = split * 16 + step;
    __syncthreads();
    #pragma unroll
    for (int c = 0; c < 4; c++) {
      int idx = c * 256 + t;
      int row = idx >> 3, ch = idx & 7;
      gld16(attT8 + (size_t)(j0 + row) * NN + (size_t)ss * 128 + ch * 16, &As[idx * 16]);
      gld16(gmT8 + (size_t)(d0 + row) * NN + (size_t)ss * 128 + ch * 16, &Bs[idx * 16]);
    }
    asm volatile("s_waitcnt vmcnt(0)" ::: "memory");
    __syncthreads();
    i32x8 af[4], bfv[4];
    #pragma unroll
    for (int mr = 0; mr < 4; mr++) af[mr] = ld_frag8(As, wm + mr * 16 + lr, lh);
    #pragma unroll
    for (int nr = 0; nr < 4; nr++) bfv[nr] = ld_frag8(Bs, wn + nr * 16 + lr, lh);
    #pragma unroll
    for (int mr = 0; mr < 4; mr++)
      #pragma unroll
      for (int nr = 0; nr < 4; nr++)
        acc[mr][nr] = __builtin_amdgcn_mfma_scale_f32_16x16x128_f8f6f4(
            af[mr], bfv[nr], acc[mr][nr], 0, 0,
            0, 0x77777777,   // A scale: 2^-8 (att stored x256)
            0, 0x7B7B7B7B);  // B scale: 2^-4 (gm stored x16)
  }
  u16* pbs = pb + (size_t)split * NN * 512;
  #pragma unroll
  for (int mr = 0; mr < 4; mr++) {
    #pragma unroll
    for (int nr = 0; nr < 4; nr++) {
      int dn = d0 + wn + nr * 16 + lr;
      #pragma unroll
      for (int r = 0; r < 4; r++) {
        int jj = j0 + wm + mr * 16 + lh * 4 + r;
        pbs[(size_t)jj * 512 + dn] = f2bf(acc[mr][nr][r]);
      }
    }
  }
}

// ---------- OLD fused aggr (fallback when ws too small) ----------
__global__ __launch_bounds__(512) void k_aggr(const u16* __restrict__ gmT,
    const u64* __restrict__ bitT, const float* __restrict__ P, const float* __restrict__ Q,
    const float* __restrict__ sq, const float* __restrict__ u, const float* __restrict__ v,
    const float* __restrict__ sk, u16* __restrict__ pb) {
  __shared__ __align__(16) u16 Alds[128 * 64];
  __shared__ __align__(16) u16 Blds[128 * 64];
  const int t = threadIdx.x, bid = blockIdx.x;
  const int lid = (bid & 7) * 128 + (bid >> 3);
  const int j_t = lid & 63, rest = lid >> 6;
  const int split = rest & 3, d_t = rest >> 2;
  const int j0 = j_t * 128, d0 = d_t * 128;
  const int lane = t & 63, w = t >> 6;
  const int lr = lane & 15, lh = lane >> 4;
  const int wm = (w >> 1) * 32, wn = (w & 1) * 64;
  const int gj = t & 127, gq = t >> 7;
  const int jg = j0 + gj;
  const float uj = u[jg], vj = v[jg], nskj = -sk[jg];
  const u64* btrow = bitT + (size_t)jg * 128;
  const f32x4 vzero = {0.f, 0.f, 0.f, 0.f};
  f32x4 acc[2][4];
  #pragma unroll
  for (int a_ = 0; a_ < 2; a_++)
    #pragma unroll
    for (int b_ = 0; b_ < 4; b_++) acc[a_][b_] = vzero;

  for (int step = 0; step < 32; step++) {
    const int ss = split * 32 + step;
    __syncthreads();
    #pragma unroll
    for (int c = 0; c < 2; c++) {
      int L = c * 512 + t;
      int dd = L >> 3, ch = L & 7;
      gld16(gmT + (size_t)(d0 + dd) * NN + ss * 64 + ch * 8, &Blds[L * 8]);
    }
    u64 word = btrow[ss];
    #pragma unroll
    for (int cc = 0; cc < 2; cc++) {
      int ig = gq + cc * 4;
      int i8 = ss * 64 + ig * 8;
      const f32x4* P4 = (const f32x4*)(P + i8);
      const f32x4* Q4 = (const f32x4*)(Q + i8);
      const f32x4* S4 = (const f32x4*)(sq + i8);
      s16x8 rr;
      #pragma unroll
      for (int hf = 0; hf < 2; hf++) {
        f32x4 pv = P4[hf], qv = Q4[hf], sv = S4[hf];
        #pragma unroll
        for (int e = 0; e < 4; e++) {
          int ie = hf * 4 + e;
          float val = (sv[e] > nskj) ? pv[e] * uj : qv[e] * vj;
          bool bit = (word >> (ig * 8 + ie)) & 1ULL;
          rr[ie] = bit ? (short)f2bf(val) : (short)0;
        }
      }
      *(s16x8*)&Alds[gj * 64 + (ig ^ (gj & 7)) * 8] = rr;
    }
    asm volatile("s_waitcnt vmcnt(0)" ::: "memory");
    __syncthreads();
    #pragma unroll
    for (int ks = 0; ks < 2; ks++) {
      s16x8 af[2], bfv[4];
      #pragma unroll
      for (int mr = 0; mr < 2; mr++) {
        int row = wm + mr * 16 + lr;
        int ch = (ks * 4 + lh) ^ (row & 7);
        af[mr] = *(const s16x8*)&Alds[row * 64 + ch * 8];
      }
      #pragma unroll
      for (int nr = 0; nr < 4; nr++) {
        int dn = wn + nr * 16 + lr;
        int ch = (ks * 4 + lh) ^ (dn & 7);
        bfv[nr] = *(const s16x8*)&Blds[dn * 64 + ch * 8];
      }
      #pragma unroll
      for (int mr = 0; mr < 2; mr++)
        #pragma unroll
        for (int nr = 0; nr < 4; nr++)
          acc[mr][nr] = __builtin_amdgcn_mfma_f32_16x16x32_bf16(af[mr], bfv[nr], acc[mr][nr], 0, 0, 0);
    }
  }
  u16* pbs = pb + (size_t)split * NN * 512;
  #pragma unroll
  for (int mr = 0; mr < 2; mr++) {
    #pragma unroll
    for (int nr = 0; nr < 4; nr++) {
      int dn = d0 + wn + nr * 16 + lr;
      #pragma unroll
      for (int r = 0; r < 4; r++) {
        int jj = j0 + wm + mr * 16 + lh * 4 + r;
        pbs[(size_t)jj * 512 + dn] = f2bf(acc[mr][nr][r]);
      }
    }
  }
}

// ---------- reduce splits + (agg+h)/2; block 2048 finalizes the loss ----------
__global__ __launch_bounds__(256) void k_reduce(const u16* __restrict__ pb,
    const float* __restrict__ h, const float* __restrict__ part, float* __restrict__ out) {
  if (blockIdx.x == 2048) {
    __shared__ float red[4];
    int t = threadIdx.x, lane = t & 63, w = t >> 6;
    float s = part[t] + part[t + 256];
    #pragma unroll
    for (int o = 32; o >= 1; o >>= 1) s += __shfl_down(s, o);
    if (lane == 0) red[w] = s;
    __syncthreads();
    if (t == 0) out[(size_t)NN * 512] = (red[0] + red[1] + red[2] + red[3]) * (1.0f / 4194304.0f);
    return;
  }
  size_t base = ((size_t)blockIdx.x * 256 + threadIdx.x) * 8;
  s16x8 p0 = *(const s16x8*)(pb + base);
  s16x8 p1 = *(const s16x8*)(pb + (size_t)NN * 512 + base);
  s16x8 p2 = *(const s16x8*)(pb + (size_t)2 * NN * 512 + base);
  s16x8 p3 = *(const s16x8*)(pb + (size_t)3 * NN * 512 + base);
  f32x4 h0 = *(const f32x4*)(h + base);
  f32x4 h1 = *(const f32x4*)(h + base + 4);
  f32x4 o0, o1;
  #pragma unroll
  for (int e = 0; e < 4; e++) {
    o0[e] = (bf2f((u16)p0[e]) + bf2f((u16)p1[e]) + bf2f((u16)p2[e]) + bf2f((u16)p3[e]) + h0[e]) * 0.5f;
    o1[e] = (bf2f((u16)p0[e + 4]) + bf2f((u16)p1[e + 4]) + bf2f((u16)p2[e + 4]) + bf2f((u16)p3[e + 4]) + h1[e]) * 0.5f;
  }
  *(f32x4*)(out + base) = o0;
  *(f32x4*)(out + base + 4) = o1;
}

extern "C" void kernel_launch(void* const* d_in, const int* in_sizes, int n_in,
                              void* d_out, int out_size, void* d_ws, size_t ws_size,
                              hipStream_t stream) {
  const float* h  = (const float*)d_in[0];
  const int*   adj= (const int*)d_in[1];
  const float* z  = (const float*)d_in[2];
  const float* Wm = (const float*)d_in[3];
  const float* bm = (const float*)d_in[4];
  const float* Wg = (const float*)d_in[5];
  const float* bg = (const float*)d_in[6];
  const float* Wk = (const float*)d_in[7];
  const float* bk = (const float*)d_in[8];
  const float* Wq = (const float*)d_in[9];
  const float* bq = (const float*)d_in[10];
  const float* a  = (const float*)d_in[11];
  float* out = (float*)d_out;
  char* ws = (char*)d_ws;

  size_t off = 0;
  auto alloc = [&](size_t b) { size_t o = off; off += (b + 255) & ~(size_t)255; return o; };
  float* wk_a = (float*)(ws + alloc(512 * 4));
  float* wq_a = (float*)(ws + alloc(512 * 4));
  float* sc   = (float*)(ws + alloc(256));
  float* skv  = (float*)(ws + alloc(NN * 4));
  float* sqv  = (float*)(ws + alloc(NN * 4));
  float* uu   = (float*)(ws + alloc(NN * 4));
  float* vv   = (float*)(ws + alloc(NN * 4));
  float* Pp   = (float*)(ws + alloc(NN * 4));
  float* Qp   = (float*)(ws + alloc(NN * 4));
  float* l1p  = (float*)(ws + alloc(512 * 4));
  u16*   WcT  = (u16*)(ws + alloc((size_t)1024 * KCAT * 2));
  u16*   gmTb = (u16*)(ws + alloc((size_t)DD * NN * 2));      // bf16 gmT (fallback) / fp8 gmT8 (big)
  u64*   bitTb= (u64*)(ws + alloc((size_t)NN * 128 * 8));
  u16*   pb   = (u16*)(ws + alloc((size_t)4 * NN * 512 * 2));

  const size_t bigNeed = (size_t)NN * NN * 2;
  bool bigPath = (ws_size >= off + bigNeed);

  if (bigPath) {
    char* big = ws + alloc(bigNeed);
    u16* Xbf  = (u16*)big;                                    // prep -> gemm1
    u16* rm   = (u16*)(big + ((size_t)10 << 20));             // gemm1 -> rowact
    u16* gate = (u16*)(big + ((size_t)19 << 20));             // gemm1 -> rowact
    u16* gm   = (u16*)(big + ((size_t)28 << 20));             // rowact -> tb(tgm8)
    u64* bits = (u64*)big;                                    // pack -> stats/tb(bitT)
    u8*  attT8= (u8*)big;                                     // attgen8 -> aggr8 (64MB)
    u8*  gmT8 = (u8*)gmTb;                                    // fp8 gmT (4MB of slot)

    k_prep<<<2597, 256, 0, stream>>>(Wk, Wq, bk, bq, a, Wm, Wg, h, z,
                                     wk_a, wq_a, sc, WcT, Xbf);
    k_gemm1<<<512, 256, 0, stream>>>(Xbf, WcT, bm, bg, rm, gate, l1p);
    k_rowact<<<8192, 256, 0, stream>>>(rm, gate, h, wk_a, wq_a, sc, gm, skv, sqv, uu, vv);
    k_pack<<<8192, 256, 0, stream>>>(adj, bits);
    k_stats<<<2048, 256, 0, stream>>>(bits, skv, uu, vv, sqv, Pp, Qp);
    k_tb<<<5120, 256, 0, stream>>>(gm, gmT8, bits, bitTb);
    k_attgen8<<<1024, 256, 0, stream>>>(bitTb, Pp, Qp, sqv, uu, vv, skv, attT8);
    k_aggr8<<<1024, 256, 0, stream>>>(attT8, gmT8, pb);
    k_reduce<<<2049, 256, 0, stream>>>(pb, h, l1p, out);
  } else {
    char* regA = ws + alloc((size_t)NN * KCAT * 2);
    char* regB = ws + alloc((size_t)NN * 512 * 2);
    char* regC = ws + alloc((size_t)NN * 512 * 2);
    u16* Xbf = (u16*)regA;  u64* bits = (u64*)regA;
    u16* rm  = (u16*)regB;
    u16* gate= (u16*)regC;
    u16* gmv = (u16*)(ws + alloc((size_t)NN * 512 * 2));
    k_prep<<<2597, 256, 0, stream>>>(Wk, Wq, bk, bq, a, Wm, Wg, h, z,
                                     wk_a, wq_a, sc, WcT, Xbf);
    k_gemm1<<<512, 256, 0, stream>>>(Xbf, WcT, bm, bg, rm, gate, l1p);
    k_rowact<<<8192, 256, 0, stream>>>(rm, gate, h, wk_a, wq_a, sc, gmv, skv, sqv, uu, vv);
    k_tgm<<<1024, 256, 0, stream>>>(gmv, gmTb);
    k_rowstats<<<8192, 256, 0, stream>>>(adj, skv, sqv, bits, Pp, Qp);
    k_bitT<<<4096, 256, 0, stream>>>(bits, bitTb);
    k_aggr<<<1024, 512, 0, stream>>>(gmTb, bitTb, Pp, Qp, sqv, uu, vv, skv, pb);
    k_reduce<<<2049, 256, 0, stream>>>(pb, h, l1p, out);
  }
}

// Round 10
// 230.998 us; speedup vs baseline: 1.1803x; 1.0464x over previous
//
#include <hip/hip_runtime.h>

typedef unsigned short u16;
typedef unsigned char u8;
typedef unsigned long long u64;
typedef short s16x8 __attribute__((ext_vector_type(8)));
typedef float f32x4 __attribute__((ext_vector_type(4)));
typedef int i32x4 __attribute__((ext_vector_type(4)));
typedef int i32x8 __attribute__((ext_vector_type(8)));

#define NN 8192
#define DD 512
#define KCAT 576

__device__ __forceinline__ u16 f2bf(float f) {
  unsigned u = __float_as_uint(f);
  unsigned r = u + 0x7fffu + ((u >> 16) & 1u);
  return (u16)(r >> 16);
}
__device__ __forceinline__ float bf2f(u16 s) {
  return __uint_as_float(((unsigned)s) << 16);
}
__device__ __forceinline__ void gld16(const void* g, void* l) {
  __builtin_amdgcn_global_load_lds((const __attribute__((address_space(1))) void*)g,
                                   (__attribute__((address_space(3))) void*)l, 16, 0, 0);
}
__device__ __forceinline__ int pk8(float f0, float f1, float f2, float f3) {
  int p = __builtin_amdgcn_cvt_pk_fp8_f32(f0, f1, 0, 0);
  p = __builtin_amdgcn_cvt_pk_fp8_f32(f2, f3, p, 1);
  return p;
}

// ---------- merged prep: [0,5): matvecs; [5,293): WcT; [293,2597): X ----------
__global__ void k_prep(const float* __restrict__ Wk, const float* __restrict__ Wq,
                       const float* __restrict__ bk, const float* __restrict__ bq,
                       const float* __restrict__ a, const float* __restrict__ Wm,
                       const float* __restrict__ Wg, const float* __restrict__ h,
                       const float* __restrict__ z, float* __restrict__ wk_a,
                       float* __restrict__ wq_a, float* __restrict__ sc,
                       u16* __restrict__ WcT, u16* __restrict__ X) {
  const int b = blockIdx.x, t = threadIdx.x;
  if (b < 5) {
    if (b < 2) {
      int c = b * 256 + t;
      float s = 0.f;
      for (int d = 0; d < 512; d++) s += Wk[(size_t)c * 512 + d] * a[d];
      wk_a[c] = s;
    } else if (b < 4) {
      int c = (b - 2) * 256 + t;
      float s = 0.f;
      for (int d = 0; d < 512; d++) s += Wq[(size_t)c * 512 + d] * a[512 + d];
      wq_a[c] = s;
    } else {
      __shared__ float red[8];
      int lane = t & 63, w = t >> 6;
      float s1 = bk[t] * a[t] + bk[t + 256] * a[t + 256];
      float s2 = bq[t] * a[512 + t] + bq[t + 256] * a[768 + t];
      #pragma unroll
      for (int o = 32; o >= 1; o >>= 1) { s1 += __shfl_down(s1, o); s2 += __shfl_down(s2, o); }
      if (lane == 0) { red[w] = s1; red[4 + w] = s2; }
      __syncthreads();
      if (t == 0) {
        sc[0] = red[0] + red[1] + red[2] + red[3];
        sc[1] = red[4] + red[5] + red[6] + red[7];
      }
    }
  } else if (b < 293) {
    int tid = (b - 5) * 256 + t;
    int n = tid / 72, g = tid % 72;
    int lg = (g & ~7) | ((g & 7) ^ (n & 7));
    int k0 = lg * 8;
    s16x8 o;
    #pragma unroll
    for (int e = 0; e < 8; e++) {
      int k = k0 + e;
      float val;
      if (n < 512) val = (k < 512) ? Wm[(size_t)k * 512 + n] : 0.f;
      else         val = Wg[(size_t)k * 512 + (n - 512)];
      o[e] = (short)f2bf(val);
    }
    *(s16x8*)&WcT[(size_t)n * KCAT + g * 8] = o;
  } else {
    int tid = (b - 293) * 256 + t;
    int i = tid / 72, g = tid % 72;
    int lg = (g & ~7) | ((g & 7) ^ (i & 7));
    int k0 = lg * 8;
    s16x8 o;
    if (k0 < 512) {
      const f32x4* s = (const f32x4*)(h + (size_t)i * 512 + k0);
      f32x4 v0 = s[0], v1 = s[1];
      #pragma unroll
      for (int e = 0; e < 4; e++) { o[e] = (short)f2bf(v0[e]); o[e + 4] = (short)f2bf(v1[e]); }
    } else {
      const f32x4* s = (const f32x4*)(z + (size_t)i * 64 + (k0 - 512));
      f32x4 v0 = s[0], v1 = s[1];
      #pragma unroll
      for (int e = 0; e < 4; e++) { o[e] = (short)f2bf(v0[e]); o[e + 4] = (short)f2bf(v1[e]); }
    }
    *(s16x8*)&X[(size_t)i * KCAT + g * 8] = o;
  }
}

// ---------- merged: [0,512) GEMM1 (MFMA-bound); [512,8704) adj bitpack (HBM-bound) ----
// Disjoint pipes co-scheduled in one dispatch: pack blocks backfill wave slots
// while gemm1 blocks own the MFMA/LDS pipes. bits buffer must NOT alias X.
__global__ __launch_bounds__(256) void k_gp(const u16* __restrict__ X,
    const u16* __restrict__ W, const float* __restrict__ bm, const float* __restrict__ bg,
    u16* __restrict__ rm, u16* __restrict__ gate, float* __restrict__ l1part,
    const int* __restrict__ adj, u64* __restrict__ bits) {
  __shared__ __align__(16) u16 As[128 * 64];
  __shared__ __align__(16) u16 Bs[128 * 64];
  __shared__ float red[4];
  const int t = threadIdx.x, bid = blockIdx.x;
  if (bid < 512) {
    const int i0 = (bid & 63) * 128, n0 = (bid >> 6) * 128;
    const int lane = t & 63, w = t >> 6;
    const int lr = lane & 15, lh = lane >> 4;
    const int wm = (w >> 1) * 64, wn = (w & 1) * 64;
    const f32x4 vz = {0.f, 0.f, 0.f, 0.f};
    f32x4 acc[4][4];
    #pragma unroll
    for (int a_ = 0; a_ < 4; a_++)
      #pragma unroll
      for (int b_ = 0; b_ < 4; b_++) acc[a_][b_] = vz;

    for (int step = 0; step < 9; step++) {
      const int kk = step * 64;
      __syncthreads();
      #pragma unroll
      for (int c = 0; c < 4; c++) {
        int L = c * 256 + t;
        int row = L >> 3, ch = L & 7;
        gld16(X + (size_t)(i0 + row) * KCAT + kk + ch * 8, &As[L * 8]);
        gld16(W + (size_t)(n0 + row) * KCAT + kk + ch * 8, &Bs[L * 8]);
      }
      asm volatile("s_waitcnt vmcnt(0)" ::: "memory");
      __syncthreads();
      #pragma unroll
      for (int ks = 0; ks < 2; ks++) {
        s16x8 af[4], bfv[4];
        #pragma unroll
        for (int mr = 0; mr < 4; mr++) {
          int row = wm + mr * 16 + lr;
          int ch = (ks * 4 + lh) ^ (row & 7);
          af[mr] = *(const s16x8*)&As[row * 64 + ch * 8];
        }
        #pragma unroll
        for (int nr = 0; nr < 4; nr++) {
          int nn = wn + nr * 16 + lr;
          int ch = (ks * 4 + lh) ^ (nn & 7);
          bfv[nr] = *(const s16x8*)&Bs[nn * 64 + ch * 8];
        }
        #pragma unroll
        for (int mr = 0; mr < 4; mr++)
          #pragma unroll
          for (int nr = 0; nr < 4; nr++)
            acc[mr][nr] = __builtin_amdgcn_mfma_f32_16x16x32_bf16(af[mr], bfv[nr], acc[mr][nr], 0, 0, 0);
      }
    }
    float lsum = 0.f;
    #pragma unroll
    for (int nr = 0; nr < 4; nr++) {
      int nn = n0 + wn + nr * 16 + lr;
      bool ismsg = nn < 512;
      float bias = ismsg ? bm[nn] : bg[nn - 512];
      #pragma unroll
      for (int mr = 0; mr < 4; mr++) {
        #pragma unroll
        for (int r = 0; r < 4; r++) {
          int row = i0 + wm + mr * 16 + lh * 4 + r;
          float v0 = acc[mr][nr][r] + bias;
          if (ismsg) {
            rm[(size_t)row * 512 + nn] = f2bf(fmaxf(v0, 0.f));
          } else {
            float g = 1.f / (1.f + __expf(-v0));
            gate[(size_t)row * 512 + (nn - 512)] = f2bf(g);
            lsum += g;
          }
        }
      }
    }
    const int lane2 = t & 63, w2 = t >> 6;
    #pragma unroll
    for (int o = 32; o >= 1; o >>= 1) lsum += __shfl_down(lsum, o);
    if (lane2 == 0) red[w2] = lsum;
    __syncthreads();
    if (t == 0) l1part[bid] = red[0] + red[1] + red[2] + red[3];
  } else {
    // pack branch: pure HBM streamer, code identical to proven k_pack
    u16* nib = As;  // reuse LDS
    const size_t i = bid - 512;
    #pragma unroll
    for (int k = 0; k < 2; k++) {
      const int4* src = (const int4*)(adj + i * NN + (size_t)(t + 256 * k) * 16);
      unsigned m = 0;
      #pragma unroll
      for (int q = 0; q < 4; q++) {
        int4 v = src[q];
        m |= (v.x > 0 ? 1u : 0u) << (4 * q);
        m |= (v.y > 0 ? 2u : 0u) << (4 * q);
        m |= (v.z > 0 ? 4u : 0u) << (4 * q);
        m |= (v.w > 0 ? 8u : 0u) << (4 * q);
      }
      nib[k * 256 + t] = (u16)m;
    }
    __syncthreads();
    if (t < 128) bits[i * 128 + t] = *(const u64*)&nib[t * 4];
  }
}

// ---------- standalone GEMM1 (fallback path) ----------
__global__ __launch_bounds__(256) void k_gemm1(const u16* __restrict__ X,
    const u16* __restrict__ W, const float* __restrict__ bm, const float* __restrict__ bg,
    u16* __restrict__ rm, u16* __restrict__ gate, float* __restrict__ l1part) {
  __shared__ __align__(16) u16 As[128 * 64];
  __shared__ __align__(16) u16 Bs[128 * 64];
  __shared__ float red[4];
  const int t = threadIdx.x, bid = blockIdx.x;
  const int i0 = (bid & 63) * 128, n0 = (bid >> 6) * 128;
  const int lane = t & 63, w = t >> 6;
  const int lr = lane & 15, lh = lane >> 4;
  const int wm = (w >> 1) * 64, wn = (w & 1) * 64;
  const f32x4 vz = {0.f, 0.f, 0.f, 0.f};
  f32x4 acc[4][4];
  #pragma unroll
  for (int a_ = 0; a_ < 4; a_++)
    #pragma unroll
    for (int b_ = 0; b_ < 4; b_++) acc[a_][b_] = vz;

  for (int step = 0; step < 9; step++) {
    const int kk = step * 64;
    __syncthreads();
    #pragma unroll
    for (int c = 0; c < 4; c++) {
      int L = c * 256 + t;
      int row = L >> 3, ch = L & 7;
      gld16(X + (size_t)(i0 + row) * KCAT + kk + ch * 8, &As[L * 8]);
      gld16(W + (size_t)(n0 + row) * KCAT + kk + ch * 8, &Bs[L * 8]);
    }
    asm volatile("s_waitcnt vmcnt(0)" ::: "memory");
    __syncthreads();
    #pragma unroll
    for (int ks = 0; ks < 2; ks++) {
      s16x8 af[4], bfv[4];
      #pragma unroll
      for (int mr = 0; mr < 4; mr++) {
        int row = wm + mr * 16 + lr;
        int ch = (ks * 4 + lh) ^ (row & 7);
        af[mr] = *(const s16x8*)&As[row * 64 + ch * 8];
      }
      #pragma unroll
      for (int nr = 0; nr < 4; nr++) {
        int nn = wn + nr * 16 + lr;
        int ch = (ks * 4 + lh) ^ (nn & 7);
        bfv[nr] = *(const s16x8*)&Bs[nn * 64 + ch * 8];
      }
      #pragma unroll
      for (int mr = 0; mr < 4; mr++)
        #pragma unroll
        for (int nr = 0; nr < 4; nr++)
          acc[mr][nr] = __builtin_amdgcn_mfma_f32_16x16x32_bf16(af[mr], bfv[nr], acc[mr][nr], 0, 0, 0);
    }
  }
  float lsum = 0.f;
  #pragma unroll
  for (int nr = 0; nr < 4; nr++) {
    int nn = n0 + wn + nr * 16 + lr;
    bool ismsg = nn < 512;
    float bias = ismsg ? bm[nn] : bg[nn - 512];
    #pragma unroll
    for (int mr = 0; mr < 4; mr++) {
      #pragma unroll
      for (int r = 0; r < 4; r++) {
        int row = i0 + wm + mr * 16 + lh * 4 + r;
        float v0 = acc[mr][nr][r] + bias;
        if (ismsg) {
          rm[(size_t)row * 512 + nn] = f2bf(fmaxf(v0, 0.f));
        } else {
          float g = 1.f / (1.f + __expf(-v0));
          gate[(size_t)row * 512 + (nn - 512)] = f2bf(g);
          lsum += g;
        }
      }
    }
  }
  #pragma unroll
  for (int o = 32; o >= 1; o >>= 1) lsum += __shfl_down(lsum, o);
  if (lane == 0) red[w] = lsum;
  __syncthreads();
  if (t == 0) l1part[bid] = red[0] + red[1] + red[2] + red[3];
}

// ---------- per-row: gm = gate*rm (bf16), sk, sq, u=e^sk, v=e^.01sk ----------
__global__ __launch_bounds__(256) void k_rowact(const u16* __restrict__ rm,
    const u16* __restrict__ gate, const float* __restrict__ h,
    const float* __restrict__ wk_a, const float* __restrict__ wq_a,
    const float* __restrict__ sc, u16* __restrict__ gm, float* __restrict__ skv,
    float* __restrict__ sqv, float* __restrict__ uu, float* __restrict__ vv) {
  __shared__ float red[8];
  const int i = blockIdx.x, t = threadIdx.x;
  const int lane = t & 63, w = t >> 6;
  float sqp = 0.f, skp = 0.f;
  #pragma unroll
  for (int rep = 0; rep < 2; rep++) {
    int d = rep * 256 + t;
    float g = bf2f(gate[(size_t)i * 512 + d]);
    float r = bf2f(rm[(size_t)i * 512 + d]);
    float p = g * r;
    gm[(size_t)i * 512 + d] = f2bf(p);
    sqp += p * wq_a[d];
    skp += h[(size_t)i * 512 + d] * wk_a[d];
  }
  #pragma unroll
  for (int o = 32; o >= 1; o >>= 1) { sqp += __shfl_down(sqp, o); skp += __shfl_down(skp, o); }
  if (lane == 0) { red[w] = skp; red[4 + w] = sqp; }
  __syncthreads();
  if (t == 0) {
    float skt = red[0] + red[1] + red[2] + red[3] + sc[0];
    float sqt = red[4] + red[5] + red[6] + red[7] + sc[1];
    skv[i] = skt; sqv[i] = sqt;
    uu[i] = __expf(skt); vv[i] = __expf(0.01f * skt);
  }
}

// ---------- merged: [0,2048) stats; [2048,3072) tgm8; [3072,7168) bitT ----------
__global__ __launch_bounds__(256) void k_tbs(const u64* __restrict__ bits,
    const float* __restrict__ sk, const float* __restrict__ uu, const float* __restrict__ vv,
    const float* __restrict__ sq, float* __restrict__ P, float* __restrict__ Q,
    const u16* __restrict__ gm, u8* __restrict__ gmT8, u64* __restrict__ bitT) {
  __shared__ __align__(16) u16 tile[64][72];
  const int bid = blockIdx.x, t = threadIdx.x;
  if (bid < 2048) {
    const int lane = t & 63, wv = t >> 6;
    const int i = bid * 4 + wv;
    const float sqi = sq[i];
    const float nsq = -sqi;
    const u64* brow = bits + (size_t)i * 128;
    float zp = 0.f, zn = 0.f, m_loc = -3.0e38f;
    for (int k = 0; k < 128; k++) {
      u64 word = brow[k];
      float skj = sk[k * 64 + lane];
      float uj = uu[k * 64 + lane];
      float vj = vv[k * 64 + lane];
      m_loc = fmaxf(m_loc, skj);
      bool msk = (word >> lane) & 1ULL;
      bool pos = skj > nsq;
      zp += (msk && pos) ? uj : 0.f;
      zn += (msk && !pos) ? vj : 0.f;
    }
    #pragma unroll
    for (int o = 32; o >= 1; o >>= 1) {
      zp += __shfl_down(zp, o);
      zn += __shfl_down(zn, o);
      m_loc = fmaxf(m_loc, __shfl_down(m_loc, o));
    }
    if (lane == 0) {
      float xk = sqi + m_loc;
      float m_i = xk >= 0.f ? xk : 0.01f * xk;
      float ep = __expf(sqi - m_i), en = __expf(0.01f * sqi - m_i);
      float Z = ep * zp + en * zn;
      float inv = 1.0f / Z;
      P[i] = ep * inv;
      Q[i] = en * inv;
    }
  } else if (bid < 3072) {
    const int b2 = bid - 2048;
    const int ti = b2 & 127, td = b2 >> 7;
    #pragma unroll
    for (int rep = 0; rep < 2; rep++) {
      int L = rep * 256 + t;
      int row = L >> 3, ch = L & 7;
      s16x8 val = *(const s16x8*)(gm + (size_t)(ti * 64 + row) * 512 + td * 64 + ch * 8);
      *(s16x8*)&tile[row][ch * 8] = val;
    }
    __syncthreads();
    const int dl = t >> 2, lc = t & 3;
    const int d = td * 64 + dl;
    const int chg = ti * 4 + lc;
    i32x4 o;
    #pragma unroll
    for (int q = 0; q < 4; q++) {
      int ib = lc * 16 + q * 4;
      o[q] = pk8(bf2f(tile[ib][dl]) * 16.f, bf2f(tile[ib + 1][dl]) * 16.f,
                 bf2f(tile[ib + 2][dl]) * 16.f, bf2f(tile[ib + 3][dl]) * 16.f);
    }
    *(i32x4*)(gmT8 + (size_t)d * NN + (chg >> 3) * 128 + ((chg & 7) ^ (d & 7)) * 16) = o;
  } else {
    int wid = (bid - 3072) * 4 + (t >> 6);
    int ti = wid & 127, tj = wid >> 7;
    int lane = t & 63;
    u64 w = bits[(size_t)(ti * 64 + lane) * 128 + tj];
    u64 out = 0;
    #pragma unroll
    for (int jj = 0; jj < 64; jj++) {
      u64 b = __ballot((int)((w >> jj) & 1ULL));
      if (jj == lane) out = b;
    }
    bitT[(size_t)(tj * 64 + lane) * 128 + ti] = out;
  }
}

// ---------- 64x64 bit-transpose via ballot (fallback) ----------
__global__ void k_bitT(const u64* __restrict__ bits, u64* __restrict__ bitT) {
  int wid = blockIdx.x * 4 + (threadIdx.x >> 6);
  int ti = wid & 127, tj = wid >> 7;
  int lane = threadIdx.x & 63;
  u64 w = bits[(size_t)(ti * 64 + lane) * 128 + tj];
  u64 out = 0;
  #pragma unroll
  for (int jj = 0; jj < 64; jj++) {
    u64 b = __ballot((int)((w >> jj) & 1ULL));
    if (jj == lane) out = b;
  }
  bitT[(size_t)(tj * 64 + lane) * 128 + ti] = out;
}

// ---------- bf16 transpose (fallback path) ----------
__global__ __launch_bounds__(256) void k_tgm(const u16* __restrict__ gm, u16* __restrict__ gmT) {
  __shared__ __align__(16) u16 tile[64][72];
  const int bid = blockIdx.x;
  const int ti = bid & 127, td = bid >> 7;
  const int t = threadIdx.x;
  #pragma unroll
  for (int rep = 0; rep < 2; rep++) {
    int L = rep * 256 + t;
    int row = L >> 3, ch = L & 7;
    s16x8 val = *(const s16x8*)(gm + (size_t)(ti * 64 + row) * 512 + td * 64 + ch * 8);
    *(s16x8*)&tile[row][ch * 8] = val;
  }
  __syncthreads();
  #pragma unroll
  for (int rep = 0; rep < 2; rep++) {
    int L = rep * 256 + t;
    int dr = L >> 3, ig = L & 7;
    int d = td * 64 + dr;
    s16x8 o;
    #pragma unroll
    for (int e = 0; e < 8; e++) o[e] = (short)tile[ig * 8 + e][dr];
    *(s16x8*)(gmT + (size_t)d * NN + ti * 64 + (ig ^ (d & 7)) * 8) = o;
  }
}

// ---------- OLD row stats (fallback path only) ----------
__global__ __launch_bounds__(256) void k_rowstats(const int* __restrict__ adj,
    const float* __restrict__ sk, const float* __restrict__ sq,
    u64* __restrict__ bits, float* __restrict__ P, float* __restrict__ Q) {
  __shared__ float sks[NN];
  __shared__ u64 bw[128];
  __shared__ float red[8];
  const int i = blockIdx.x, t = threadIdx.x;
  const int lane = t & 63, w = t >> 6;
  const int* arow = adj + (size_t)i * NN;
  float kmax = -3.0e38f;
  for (int c = 0; c < 32; c++) {
    int j = c * 256 + t;
    int av = arow[j];
    float skj = sk[j];
    sks[j] = skj;
    bool bit = av > 0;
    u64 m = __ballot(bit);
    if (lane == 0) bw[c * 4 + w] = m;
    if (bit) kmax = fmaxf(kmax, skj);
  }
  #pragma unroll
  for (int o = 32; o >= 1; o >>= 1) kmax = fmaxf(kmax, __shfl_down(kmax, o));
  if (lane == 0) red[w] = kmax;
  __syncthreads();
  float K = fmaxf(fmaxf(red[0], red[1]), fmaxf(red[2], red[3]));
  float sqi = sq[i];
  float xk = sqi + K;
  float m_i = xk >= 0.f ? xk : 0.01f * xk;
  float s = 0.f;
  for (int c = 0; c < 32; c++) {
    int j = c * 256 + t;
    u64 mw = bw[c * 4 + w];
    float xx = sqi + sks[j];
    float f = xx >= 0.f ? xx : 0.01f * xx;
    float e = __expf(f - m_i);
    if ((mw >> lane) & 1ULL) s += e;
  }
  #pragma unroll
  for (int o = 32; o >= 1; o >>= 1) s += __shfl_down(s, o);
  if (lane == 0) red[4 + w] = s;
  __syncthreads();
  if (t == 0) {
    float Z = red[4] + red[5] + red[6] + red[7];
    float inv = 1.0f / Z;
    P[i] = __expf(sqi - m_i) * inv;
    Q[i] = __expf(0.01f * sqi - m_i) * inv;
  }
  if (t < 128) bits[(size_t)i * 128 + t] = bw[t];
}

// ---------- attgen8: attT8[j][i] = fp8(att*256), chunk16 swizzle in 128-i windows ----
__global__ __launch_bounds__(256) void k_attgen8(const u64* __restrict__ bitT,
    const float* __restrict__ P, const float* __restrict__ Q, const float* __restrict__ sq,
    const float* __restrict__ u, const float* __restrict__ v, const float* __restrict__ sk,
    u8* __restrict__ attT8) {
  const int t = threadIdx.x, bid = blockIdx.x;
  const int jt = bid >> 1, ih = bid & 1;
  const int j0 = jt * 16;
  const int i0 = ih * 4096 + t * 16;
  f32x4 Pv[4], Qv[4], Sv[4];
  #pragma unroll
  for (int q = 0; q < 4; q++) {
    Pv[q] = *(const f32x4*)(P + i0 + q * 4);
    Qv[q] = *(const f32x4*)(Q + i0 + q * 4);
    Sv[q] = *(const f32x4*)(sq + i0 + q * 4);
  }
  const int widx = i0 >> 6;
  const int bsh = (t & 3) * 16;
  const int chg = i0 >> 4;
  const int wnd = chg >> 3, cs = chg & 7;
  #pragma unroll 2
  for (int r = 0; r < 16; r++) {
    const int j = j0 + r;
    const float uj = u[j] * 256.f, vj = v[j] * 256.f, nskj = -sk[j];
    const u64 w64 = bitT[(size_t)j * 128 + widx];
    const unsigned m16 = (unsigned)(w64 >> bsh) & 0xFFFFu;
    i32x4 o;
    #pragma unroll
    for (int q = 0; q < 4; q++) {
      float f[4];
      #pragma unroll
      for (int e = 0; e < 4; e++) {
        bool pos = Sv[q][e] > nskj;
        float val = pos ? Pv[q][e] * uj : Qv[q][e] * vj;
        f[e] = ((m16 >> (q * 4 + e)) & 1u) ? val : 0.f;
      }
      o[q] = pk8(f[0], f[1], f[2], f[3]);
    }
    *(i32x4*)(attT8 + (size_t)j * NN + wnd * 128 + ((cs ^ (j & 7)) * 16)) = o;
  }
}

// ---------- aggr8: MX-fp8 GEMM (K=128/step), pb[split][j][d] ----------
__device__ __forceinline__ i32x8 ld_frag8(const u8* base, int row, int lh) {
  const int c0 = ((2 * lh) ^ (row & 7)) * 16;
  const int c1 = ((2 * lh + 1) ^ (row & 7)) * 16;
  i32x4 lo = *(const i32x4*)(base + row * 128 + c0);
  i32x4 hi = *(const i32x4*)(base + row * 128 + c1);
  i32x8 r;
  r[0] = lo[0]; r[1] = lo[1]; r[2] = lo[2]; r[3] = lo[3];
  r[4] = hi[0]; r[5] = hi[1]; r[6] = hi[2]; r[7] = hi[3];
  return r;
}

__global__ __launch_bounds__(256) void k_aggr8(const u8* __restrict__ attT8,
    const u8* __restrict__ gmT8, u16* __restrict__ pb) {
  __shared__ __align__(16) u8 As[128 * 128];
  __shared__ __align__(16) u8 Bs[128 * 128];
  const int t = threadIdx.x, bid = blockIdx.x;
  const int lid = (bid & 7) * 128 + (bid >> 3);
  const int dt = lid & 3, jt = (lid >> 2) & 63, split = lid >> 8;
  const int j0 = jt * 128, d0 = dt * 128;
  const int lane = t & 63, w = t >> 6;
  const int lr = lane & 15, lh = lane >> 4;
  const int wm = (w >> 1) * 64, wn = (w & 1) * 64;
  const f32x4 vz = {0.f, 0.f, 0.f, 0.f};
  f32x4 acc[4][4];
  #pragma unroll
  for (int a_ = 0; a_ < 4; a_++)
    #pragma unroll
    for (int b_ = 0; b_ < 4; b_++) acc[a_][b_] = vz;

  for (int step = 0; step < 16; step++) {
    const int ss = split * 16 + step;
    __syncthreads();
    #pragma unroll
    for (int c = 0; c < 4; c++) {
      int idx = c * 256 + t;
      int row = idx >> 3, ch = idx & 7;
      gld16(attT8 + (size_t)(j0 + row) * NN + (size_t)ss * 128 + ch * 16, &As[idx * 16]);
      gld16(gmT8 + (size_t)(d0 + row) * NN + (size_t)ss * 128 + ch * 16, &Bs[idx * 16]);
    }
    asm volatile("s_waitcnt vmcnt(0)" ::: "memory");
    __syncthreads();
    i32x8 af[4], bfv[4];
    #pragma unroll
    for (int mr = 0; mr < 4; mr++) af[mr] = ld_frag8(As, wm + mr * 16 + lr, lh);
    #pragma unroll
    for (int nr = 0; nr < 4; nr++) bfv[nr] = ld_frag8(Bs, wn + nr * 16 + lr, lh);
    #pragma unroll
    for (int mr = 0; mr < 4; mr++)
      #pragma unroll
      for (int nr = 0; nr < 4; nr++)
        acc[mr][nr] = __builtin_amdgcn_mfma_scale_f32_16x16x128_f8f6f4(
            af[mr], bfv[nr], acc[mr][nr], 0, 0,
            0, 0x77777777,   // A scale: 2^-8 (att stored x256)
            0, 0x7B7B7B7B);  // B scale: 2^-4 (gm stored x16)
  }
  u16* pbs = pb + (size_t)split * NN * 512;
  #pragma unroll
  for (int mr = 0; mr < 4; mr++) {
    #pragma unroll
    for (int nr = 0; nr < 4; nr++) {
      int dn = d0 + wn + nr * 16 + lr;
      #pragma unroll
      for (int r = 0; r < 4; r++) {
        int jj = j0 + wm + mr * 16 + lh * 4 + r;
        pbs[(size_t)jj * 512 + dn] = f2bf(acc[mr][nr][r]);
      }
    }
  }
}

// ---------- OLD fused aggr (fallback when ws too small) ----------
__global__ __launch_bounds__(512) void k_aggr(const u16* __restrict__ gmT,
    const u64* __restrict__ bitT, const float* __restrict__ P, const float* __restrict__ Q,
    const float* __restrict__ sq, const float* __restrict__ u, const float* __restrict__ v,
    const float* __restrict__ sk, u16* __restrict__ pb) {
  __shared__ __align__(16) u16 Alds[128 * 64];
  __shared__ __align__(16) u16 Blds[128 * 64];
  const int t = threadIdx.x, bid = blockIdx.x;
  const int lid = (bid & 7) * 128 + (bid >> 3);
  const int j_t = lid & 63, rest = lid >> 6;
  const int split = rest & 3, d_t = rest >> 2;
  const int j0 = j_t * 128, d0 = d_t * 128;
  const int lane = t & 63, w = t >> 6;
  const int lr = lane & 15, lh = lane >> 4;
  const int wm = (w >> 1) * 32, wn = (w & 1) * 64;
  const int gj = t & 127, gq = t >> 7;
  const int jg = j0 + gj;
  const float uj = u[jg], vj = v[jg], nskj = -sk[jg];
  const u64* btrow = bitT + (size_t)jg * 128;
  const f32x4 vzero = {0.f, 0.f, 0.f, 0.f};
  f32x4 acc[2][4];
  #pragma unroll
  for (int a_ = 0; a_ < 2; a_++)
    #pragma unroll
    for (int b_ = 0; b_ < 4; b_++) acc[a_][b_] = vzero;

  for (int step = 0; step < 32; step++) {
    const int ss = split * 32 + step;
    __syncthreads();
    #pragma unroll
    for (int c = 0; c < 2; c++) {
      int L = c * 512 + t;
      int dd = L >> 3, ch = L & 7;
      gld16(gmT + (size_t)(d0 + dd) * NN + ss * 64 + ch * 8, &Blds[L * 8]);
    }
    u64 word = btrow[ss];
    #pragma unroll
    for (int cc = 0; cc < 2; cc++) {
      int ig = gq + cc * 4;
      int i8 = ss * 64 + ig * 8;
      const f32x4* P4 = (const f32x4*)(P + i8);
      const f32x4* Q4 = (const f32x4*)(Q + i8);
      const f32x4* S4 = (const f32x4*)(sq + i8);
      s16x8 rr;
      #pragma unroll
      for (int hf = 0; hf < 2; hf++) {
        f32x4 pv = P4[hf], qv = Q4[hf], sv = S4[hf];
        #pragma unroll
        for (int e = 0; e < 4; e++) {
          int ie = hf * 4 + e;
          float val = (sv[e] > nskj) ? pv[e] * uj : qv[e] * vj;
          bool bit = (word >> (ig * 8 + ie)) & 1ULL;
          rr[ie] = bit ? (short)f2bf(val) : (short)0;
        }
      }
      *(s16x8*)&Alds[gj * 64 + (ig ^ (gj & 7)) * 8] = rr;
    }
    asm volatile("s_waitcnt vmcnt(0)" ::: "memory");
    __syncthreads();
    #pragma unroll
    for (int ks = 0; ks < 2; ks++) {
      s16x8 af[2], bfv[4];
      #pragma unroll
      for (int mr = 0; mr < 2; mr++) {
        int row = wm + mr * 16 + lr;
        int ch = (ks * 4 + lh) ^ (row & 7);
        af[mr] = *(const s16x8*)&Alds[row * 64 + ch * 8];
      }
      #pragma unroll
      for (int nr = 0; nr < 4; nr++) {
        int dn = wn + nr * 16 + lr;
        int ch = (ks * 4 + lh) ^ (dn & 7);
        bfv[nr] = *(const s16x8*)&Blds[dn * 64 + ch * 8];
      }
      #pragma unroll
      for (int mr = 0; mr < 2; mr++)
        #pragma unroll
        for (int nr = 0; nr < 4; nr++)
          acc[mr][nr] = __builtin_amdgcn_mfma_f32_16x16x32_bf16(af[mr], bfv[nr], acc[mr][nr], 0, 0, 0);
    }
  }
  u16* pbs = pb + (size_t)split * NN * 512;
  #pragma unroll
  for (int mr = 0; mr < 2; mr++) {
    #pragma unroll
    for (int nr = 0; nr < 4; nr++) {
      int dn = d0 + wn + nr * 16 + lr;
      #pragma unroll
      for (int r = 0; r < 4; r++) {
        int jj = j0 + wm + mr * 16 + lh * 4 + r;
        pbs[(size_t)jj * 512 + dn] = f2bf(acc[mr][nr][r]);
      }
    }
  }
}

// ---------- reduce splits + (agg+h)/2; block 2048 finalizes the loss ----------
__global__ __launch_bounds__(256) void k_reduce(const u16* __restrict__ pb,
    const float* __restrict__ h, const float* __restrict__ part, float* __restrict__ out) {
  if (blockIdx.x == 2048) {
    __shared__ float red[4];
    int t = threadIdx.x, lane = t & 63, w = t >> 6;
    float s = part[t] + part[t + 256];
    #pragma unroll
    for (int o = 32; o >= 1; o >>= 1) s += __shfl_down(s, o);
    if (lane == 0) red[w] = s;
    __syncthreads();
    if (t == 0) out[(size_t)NN * 512] = (red[0] + red[1] + red[2] + red[3]) * (1.0f / 4194304.0f);
    return;
  }
  size_t base = ((size_t)blockIdx.x * 256 + threadIdx.x) * 8;
  s16x8 p0 = *(const s16x8*)(pb + base);
  s16x8 p1 = *(const s16x8*)(pb + (size_t)NN * 512 + base);
  s16x8 p2 = *(const s16x8*)(pb + (size_t)2 * NN * 512 + base);
  s16x8 p3 = *(const s16x8*)(pb + (size_t)3 * NN * 512 + base);
  f32x4 h0 = *(const f32x4*)(h + base);
  f32x4 h1 = *(const f32x4*)(h + base + 4);
  f32x4 o0, o1;
  #pragma unroll
  for (int e = 0; e < 4; e++) {
    o0[e] = (bf2f((u16)p0[e]) + bf2f((u16)p1[e]) + bf2f((u16)p2[e]) + bf2f((u16)p3[e]) + h0[e]) * 0.5f;
    o1[e] = (bf2f((u16)p0[e + 4]) + bf2f((u16)p1[e + 4]) + bf2f((u16)p2[e + 4]) + bf2f((u16)p3[e + 4]) + h1[e]) * 0.5f;
  }
  *(f32x4*)(out + base) = o0;
  *(f32x4*)(out + base + 4) = o1;
}

extern "C" void kernel_launch(void* const* d_in, const int* in_sizes, int n_in,
                              void* d_out, int out_size, void* d_ws, size_t ws_size,
                              hipStream_t stream) {
  const float* h  = (const float*)d_in[0];
  const int*   adj= (const int*)d_in[1];
  const float* z  = (const float*)d_in[2];
  const float* Wm = (const float*)d_in[3];
  const float* bm = (const float*)d_in[4];
  const float* Wg = (const float*)d_in[5];
  const float* bg = (const float*)d_in[6];
  const float* Wk = (const float*)d_in[7];
  const float* bk = (const float*)d_in[8];
  const float* Wq = (const float*)d_in[9];
  const float* bq = (const float*)d_in[10];
  const float* a  = (const float*)d_in[11];
  float* out = (float*)d_out;
  char* ws = (char*)d_ws;

  size_t off = 0;
  auto alloc = [&](size_t b) { size_t o = off; off += (b + 255) & ~(size_t)255; return o; };
  float* wk_a = (float*)(ws + alloc(512 * 4));
  float* wq_a = (float*)(ws + alloc(512 * 4));
  float* sc   = (float*)(ws + alloc(256));
  float* skv  = (float*)(ws + alloc(NN * 4));
  float* sqv  = (float*)(ws + alloc(NN * 4));
  float* uu   = (float*)(ws + alloc(NN * 4));
  float* vv   = (float*)(ws + alloc(NN * 4));
  float* Pp   = (float*)(ws + alloc(NN * 4));
  float* Qp   = (float*)(ws + alloc(NN * 4));
  float* l1p  = (float*)(ws + alloc(512 * 4));
  u16*   WcT  = (u16*)(ws + alloc((size_t)1024 * KCAT * 2));
  u16*   gmTb = (u16*)(ws + alloc((size_t)DD * NN * 2));      // bf16 gmT (fallback) / fp8 gmT8 (big)
  u64*   bitTb= (u64*)(ws + alloc((size_t)NN * 128 * 8));
  u64*   bitsB= (u64*)(ws + alloc((size_t)NN * 128 * 8));     // bits — own slot (co-lives with X)
  u16*   pb   = (u16*)(ws + alloc((size_t)4 * NN * 512 * 2));

  const size_t bigNeed = (size_t)NN * NN * 2;
  bool bigPath = (ws_size >= off + bigNeed);

  if (bigPath) {
    char* big = ws + alloc(bigNeed);
    u16* Xbf  = (u16*)big;                                    // prep -> gp(gemm1)
    u16* rm   = (u16*)(big + ((size_t)10 << 20));             // gp -> rowact
    u16* gate = (u16*)(big + ((size_t)19 << 20));             // gp -> rowact
    u16* gm   = (u16*)(big + ((size_t)28 << 20));             // rowact -> tbs(tgm8)
    u8*  attT8= (u8*)big;                                     // attgen8 -> aggr8 (64MB)
    u8*  gmT8 = (u8*)gmTb;                                    // fp8 gmT (4MB of slot)

    k_prep<<<2597, 256, 0, stream>>>(Wk, Wq, bk, bq, a, Wm, Wg, h, z,
                                     wk_a, wq_a, sc, WcT, Xbf);
    k_gp<<<8704, 256, 0, stream>>>(Xbf, WcT, bm, bg, rm, gate, l1p, adj, bitsB);
    k_rowact<<<8192, 256, 0, stream>>>(rm, gate, h, wk_a, wq_a, sc, gm, skv, sqv, uu, vv);
    k_tbs<<<7168, 256, 0, stream>>>(bitsB, skv, uu, vv, sqv, Pp, Qp, gm, gmT8, bitTb);
    k_attgen8<<<1024, 256, 0, stream>>>(bitTb, Pp, Qp, sqv, uu, vv, skv, attT8);
    k_aggr8<<<1024, 256, 0, stream>>>(attT8, gmT8, pb);
    k_reduce<<<2049, 256, 0, stream>>>(pb, h, l1p, out);
  } else {
    char* regA = ws + alloc((size_t)NN * KCAT * 2);
    char* regB = ws + alloc((size_t)NN * 512 * 2);
    char* regC = ws + alloc((size_t)NN * 512 * 2);
    u16* Xbf = (u16*)regA;  u64* bits = (u64*)regA;
    u16* rm  = (u16*)regB;
    u16* gate= (u16*)regC;
    u16* gmv = (u16*)(ws + alloc((size_t)NN * 512 * 2));
    k_prep<<<2597, 256, 0, stream>>>(Wk, Wq, bk, bq, a, Wm, Wg, h, z,
                                     wk_a, wq_a, sc, WcT, Xbf);
    k_gemm1<<<512, 256, 0, stream>>>(Xbf, WcT, bm, bg, rm, gate, l1p);
    k_rowact<<<8192, 256, 0, stream>>>(rm, gate, h, wk_a, wq_a, sc, gmv, skv, sqv, uu, vv);
    k_tgm<<<1024, 256, 0, stream>>>(gmv, gmTb);
    k_rowstats<<<8192, 256, 0, stream>>>(adj, skv, sqv, bits, Pp, Qp);
    k_bitT<<<4096, 256, 0, stream>>>(bits, bitTb);
    k_aggr<<<1024, 512, 0, stream>>>(gmTb, bitTb, Pp, Qp, sqv, uu, vv, skv, pb);
    k_reduce<<<2049, 256, 0, stream>>>(pb, h, l1p, out);
  }
}